// Round 13
// baseline (4813.833 us; speedup 1.0000x reference)
//
#include <hip/hip_runtime.h>
#include <utility>

#define HID 256

typedef __attribute__((ext_vector_type(8))) short bf16x8;
typedef __attribute__((ext_vector_type(4))) float f32x4;
typedef __attribute__((ext_vector_type(4))) unsigned short us4;
typedef __attribute__((ext_vector_type(8))) unsigned short us8;

// Topology constants for GRID_N=80
constexpr size_t MAXN3 = 100489;
constexpr size_t MAXE3 = 300200;

// Tiled-weight offsets (elements). Per matrix: [4 cb][K/64 ktb][4096 bf16],
// tile content pre-swizzled so a LINEAR global_load_lds produces the swizzled image.
constexpr size_t OFF_IN1 = 0;                       // 2 mats K=128
constexpr size_t OFF_IN2 = OFF_IN1 + 2 * 256 * 128; // 2 mats K=384
constexpr size_t OFF_IN3 = OFF_IN2 + 2 * 256 * 384;
constexpr size_t OFF_H1  = OFF_IN3 + 2 * 256 * 384; // 24 mats K=256
constexpr size_t OFF_H2  = OFF_H1 + 24 * 256 * 256;
constexpr size_t OFF_H3  = OFF_H2 + 24 * 256 * 256;
constexpr size_t WT_TOTAL = OFF_H3 + 24 * 256 * 256;

// Static device scratch (BSS — graph-capture safe). Features = split bf16
// hi/lo PLANES: x == b2f(hi) + b2f(lo) exactly.
__device__ __attribute__((aligned(16))) unsigned short g_Ah[MAXN3 * 256];
__device__ __attribute__((aligned(16))) unsigned short g_Al[MAXN3 * 256];
__device__ __attribute__((aligned(16))) unsigned short g_Bh[MAXN3 * 256];
__device__ __attribute__((aligned(16))) unsigned short g_Bl[MAXN3 * 256];
__device__ __attribute__((aligned(16))) unsigned short g_Gh[MAXN3 * 256];
__device__ __attribute__((aligned(16))) unsigned short g_Gl[MAXN3 * 256];
__device__ __attribute__((aligned(16))) unsigned short g_Dh[MAXN3 * 256];
__device__ __attribute__((aligned(16))) unsigned short g_Dl[MAXN3 * 256];
__device__ __attribute__((aligned(16))) unsigned short g_VAh[MAXN3 * 128];
__device__ __attribute__((aligned(16))) unsigned short g_VAl[MAXN3 * 128];
__device__ float g_C0[MAXN3 * 3];
__device__ float g_C2[MAXN3 * 3];
__device__ float g_Vv[MAXN3 * 3];
__device__ float g_T [56 * 56 * 128];
__device__ __attribute__((aligned(16))) unsigned short g_Wth[WT_TOTAL];
__device__ __attribute__((aligned(16))) unsigned short g_Wtl[WT_TOTAL];
// CSR scratch
__device__ int g_deg   [MAXN3];
__device__ int g_rowptr[MAXN3 + 1];
__device__ int g_cursor[MAXN3];
__device__ int g_adj   [2 * MAXE3];
__device__ int g_bsum  [128];

__device__ inline float b2f(unsigned short h) {
  return __uint_as_float((unsigned)h << 16);
}
__device__ inline void fsplit(float f, unsigned short& h, unsigned short& l) {
  unsigned u = __float_as_uint(f);
  h = (unsigned short)(u >> 16);
  float hf = __uint_as_float(u & 0xffff0000u);
  l = (unsigned short)(__float_as_uint(f - hf) >> 16);
}

#define GLOAD16(g, l)                                                       \
  __builtin_amdgcn_global_load_lds(                                        \
      (const __attribute__((address_space(1))) unsigned*)(const void*)(g), \
      (__attribute__((address_space(3))) unsigned*)(void*)(l), 16, 0, 0)

// ---------------- weight transpose + split + tile-swizzle (BK=64 tiles) ----------------
// Out tile chunk c (n=c>>3, sp=c&7) holds W^T[cb*64+n][ktb*64+(sp^(n&7))*8 .. +7]
__global__ __launch_bounds__(256) void k_wtrans(const float* __restrict__ W,
                                                unsigned short* __restrict__ Oh,
                                                unsigned short* __restrict__ Ol,
                                                int K) {
  __shared__ float Ls[64][65];
  int ktb = blockIdx.x, cb = blockIdx.y, mat = blockIdx.z;
  int nktb = gridDim.x;
  const float* Wm = W + (size_t)mat * K * 256;
  int t = threadIdx.x;
#pragma unroll
  for (int i = 0; i < 16; ++i) {
    int idx = i * 256 + t;
    int kk = idx >> 6, cc = idx & 63;
    Ls[kk][cc] = Wm[(size_t)(ktb * 64 + kk) * 256 + cb * 64 + cc];
  }
  __syncthreads();
  size_t tb = ((size_t)(mat * 4 + cb) * nktb + ktb) * 4096;
#pragma unroll
  for (int i = 0; i < 2; ++i) {
    int c = t * 2 + i;
    int n = c >> 3, sp = c & 7;
    int kbase = (sp ^ (n & 7)) * 8;
    unsigned short hb[8], lb[8];
#pragma unroll
    for (int j = 0; j < 8; ++j) {
      float v = Ls[kbase + j][n];
      unsigned short hi, lo;
      fsplit(v, hi, lo);
      hb[j] = hi;
      lb[j] = lo;
    }
    *(us4*)(Oh + tb + c * 8)     = (us4){hb[0], hb[1], hb[2], hb[3]};
    *(us4*)(Oh + tb + c * 8 + 4) = (us4){hb[4], hb[5], hb[6], hb[7]};
    *(us4*)(Ol + tb + c * 8)     = (us4){lb[0], lb[1], lb[2], lb[3]};
    *(us4*)(Ol + tb + c * 8 + 4) = (us4){lb[4], lb[5], lb[6], lb[7]};
  }
}

// ---------------- CSR build (parallel scan) ----------------

__global__ __launch_bounds__(256) void k_count(const int* __restrict__ edges,
                                               int* __restrict__ deg, int E) {
  int e = blockIdx.x * blockDim.x + threadIdx.x;
  if (e >= E) return;
  atomicAdd(&deg[edges[2 * e + 0]], 1);
  atomicAdd(&deg[edges[2 * e + 1]], 1);
}

__global__ __launch_bounds__(256) void k_scan_part(const int* __restrict__ deg,
                                                   int* __restrict__ bsum, int N) {
  __shared__ int s[256];
  int t = threadIdx.x;
  int base = blockIdx.x * 1024 + t * 4;
  int v = 0;
#pragma unroll
  for (int i = 0; i < 4; ++i) {
    int idx = base + i;
    if (idx < N) v += deg[idx];
  }
  s[t] = v;
  __syncthreads();
  for (int off = 128; off > 0; off >>= 1) {
    if (t < off) s[t] += s[t + off];
    __syncthreads();
  }
  if (t == 0) bsum[blockIdx.x] = s[0];
}

__global__ __launch_bounds__(128) void k_scan_top(int* __restrict__ bsum, int nb) {
  __shared__ int s[128];
  int t = threadIdx.x;
  s[t] = (t < nb) ? bsum[t] : 0;
  __syncthreads();
  for (int off = 1; off < 128; off <<= 1) {
    int v = (t >= off) ? s[t - off] : 0;
    __syncthreads();
    s[t] += v;
    __syncthreads();
  }
  if (t < nb) bsum[t] = (t == 0) ? 0 : s[t - 1];
}

__global__ __launch_bounds__(256) void k_scan_write(const int* __restrict__ deg,
                                                    const int* __restrict__ bsum,
                                                    int* __restrict__ rowptr,
                                                    int* __restrict__ cursor, int N) {
  __shared__ int s[256];
  int t = threadIdx.x;
  int base = blockIdx.x * 1024;
  int d[4];
  int local = 0;
#pragma unroll
  for (int i = 0; i < 4; ++i) {
    int idx = base + t * 4 + i;
    d[i] = (idx < N) ? deg[idx] : 0;
    local += d[i];
  }
  s[t] = local;
  __syncthreads();
  for (int off = 1; off < 256; off <<= 1) {
    int v = (t >= off) ? s[t - off] : 0;
    __syncthreads();
    s[t] += v;
    __syncthreads();
  }
  int run = bsum[blockIdx.x] + s[t] - local;
#pragma unroll
  for (int i = 0; i < 4; ++i) {
    int idx = base + t * 4 + i;
    if (idx < N) {
      rowptr[idx] = run;
      cursor[idx] = run;
    }
    run += d[i];
  }
  if (blockIdx.x == gridDim.x - 1 && t == 255) rowptr[N] = run;
}

__global__ __launch_bounds__(256) void k_fill(const int* __restrict__ edges,
                                              int* __restrict__ cursor,
                                              int* __restrict__ adj, int E) {
  int e = blockIdx.x * blockDim.x + threadIdx.x;
  if (e >= E) return;
  int a = edges[2 * e + 0];
  int b = edges[2 * e + 1];
  adj[atomicAdd(&cursor[a], 1)] = b;
  adj[atomicAdd(&cursor[b], 1)] = a;
}

// ---------------- misc kernels ----------------

__global__ __launch_bounds__(128) void k_transpose(const float* __restrict__ in,
                                                   float* __restrict__ out, int HW) {
  int p = blockIdx.x;
  int c = threadIdx.x;
  if (p < HW) out[(size_t)p * 128 + c] = in[(size_t)c * HW + p];
}

__global__ __launch_bounds__(128) void k_vert_align(const float* __restrict__ fT,
                                                    const float* __restrict__ verts,
                                                    unsigned short* __restrict__ oh,
                                                    unsigned short* __restrict__ ol,
                                                    int N, int H, int W) {
  int v = blockIdx.x;
  if (v >= N) return;
  int c = threadIdx.x;
  float vx = verts[(size_t)v * 3 + 0];
  float vy = verts[(size_t)v * 3 + 1];
  float fx = (vx + 1.f) * 0.5f * (float)(W - 1);
  float fy = (vy + 1.f) * 0.5f * (float)(H - 1);
  float x0f = floorf(fx), y0f = floorf(fy);
  float wx = fx - x0f, wy = fy - y0f;
  int x0 = (int)x0f, y0 = (int)y0f;
  float acc = 0.f;
#pragma unroll
  for (int dy = 0; dy < 2; ++dy) {
#pragma unroll
    for (int dx = 0; dx < 2; ++dx) {
      int yi = y0 + dy, xi = x0 + dx;
      bool valid = (yi >= 0) && (yi < H) && (xi >= 0) && (xi < W);
      int yc = min(max(yi, 0), H - 1);
      int xc = min(max(xi, 0), W - 1);
      float val = fT[((size_t)yc * W + xc) * 128 + c];
      float wgt = (dy ? wy : 1.f - wy) * (dx ? wx : 1.f - wx);
      acc += valid ? val * wgt : 0.f;
    }
  }
  unsigned short h, l;
  fsplit(acc, h, l);
  oh[(size_t)v * 128 + c] = h;
  ol[(size_t)v * 128 + c] = l;
}

// G[v] = split( sum_{u in adj(v)} (b2f(Xh[u]) + b2f(Xl[u])) ), 8 ch/thread
template <int CH>
__global__ __launch_bounds__(256) void k_gather(const int* __restrict__ rowptr,
                                                const int* __restrict__ adj,
                                                const unsigned short* __restrict__ Xh,
                                                const unsigned short* __restrict__ Xl,
                                                unsigned short* __restrict__ Gh,
                                                unsigned short* __restrict__ Gl, int N) {
  constexpr int TPV = CH / 8;
  int idx = blockIdx.x * blockDim.x + threadIdx.x;
  int v = idx / TPV;
  if (v >= N) return;
  int c = (idx % TPV) * 8;
  float a[8] = {};
  int lo = rowptr[v], hi = rowptr[v + 1];
  for (int i = lo; i < hi; ++i) {
    size_t base = (size_t)adj[i] * CH + c;
    us8 h = *(const us8*)(Xh + base);
    us8 l = *(const us8*)(Xl + base);
#pragma unroll
    for (int j = 0; j < 8; ++j) a[j] += b2f(h[j]) + b2f(l[j]);
  }
  us8 oh, ol;
#pragma unroll
  for (int j = 0; j < 8; ++j) {
    unsigned short hh, ll;
    fsplit(a[j], hh, ll);
    oh[j] = hh;
    ol[j] = ll;
  }
  *(us8*)(Gh + (size_t)v * CH + c) = oh;
  *(us8*)(Gl + (size_t)v * CH + c) = ol;
}

// ---- split-plane MFMA layer (128x128 tile, BK=64, dbuf + counted vmcnt) ----
struct Panels {
  const unsigned short* ph[4];
  const unsigned short* pl[4];
  int ks[4];
  int ld[4];
};

// involution swizzle: LDS[row][s] holds source chunk s^(row&7); 8-bf16 chunks
#define SWZ(row, slot) (((row) * 64) + (((slot) ^ ((row) & 7)) << 3))

__global__ __launch_bounds__(512, 2) void k_layer(
    Panels pd, int Kmm,
    const unsigned short* __restrict__ w0h, const unsigned short* __restrict__ w0l,
    const unsigned short* __restrict__ w1h, const unsigned short* __restrict__ w1l,
    int Kw,
    const float* __restrict__ b0, const float* __restrict__ b1,
    const int* __restrict__ deg,
    unsigned short* __restrict__ Yh, unsigned short* __restrict__ Yl, int N) {
  // 128 KB: double-buffered X (2x16KB/plane) + W (2 col-halves, 2x16KB/plane)
  __shared__ __attribute__((aligned(16))) unsigned short Xh_lds[2][128 * 64];
  __shared__ __attribute__((aligned(16))) unsigned short Xl_lds[2][128 * 64];
  __shared__ __attribute__((aligned(16))) unsigned short Wh_lds[2][2 * 4096];
  __shared__ __attribute__((aligned(16))) unsigned short Wl_lds[2][2 * 4096];
  int tid = threadIdx.x;
  int lane = tid & 63;
  int wid = tid >> 6;          // 0..7
  int wm = wid >> 2;           // 0..1 (64-row half)
  int wn = wid & 3;            // 0..3 (32-col group)

  // XCD-aware swizzle: groups of 8 row-tiles x 2 col-blocks
  int nrt = (N + 127) >> 7;
  int total = nrt * 2;
  int flat = blockIdx.x;
  int rowtile, colblk;
  if ((flat & ~15) + 16 <= total) {
    int sub = flat & 15;
    rowtile = (flat >> 4) * 8 + (sub & 7);
    colblk = sub >> 3;
  } else {
    rowtile = flat >> 1;
    colblk = flat & 1;
  }
  int row0 = rowtile * 128;
  int col0 = colblk * 128;
  int nktbw = Kw >> 6;

  f32x4 acc[4][2];
#pragma unroll
  for (int m = 0; m < 4; ++m)
#pragma unroll
    for (int n = 0; n < 2; ++n) acc[m][n] = (f32x4){0.f, 0.f, 0.f, 0.f};

  // 8 global_load_lds per wave per STAGE (4 X + 4 W)
  auto STAGE = [&](int buf, int kt) {
    int pi = (kt >= pd.ks[1]) + (kt >= pd.ks[2]) + (kt >= pd.ks[3]);
    const unsigned short* bph = pd.ph[pi];
    const unsigned short* bpl = pd.pl[pi];
    int ld = pd.ld[pi];
    int koff = kt - pd.ks[pi];
#pragma unroll
    for (int i = 0; i < 2; ++i) {
      int c = tid + i * 512;           // 0..1023 16B chunks
      int row = c >> 3, slot = c & 7;
      int vg = min(row0 + row, N - 1);
      size_t so = (size_t)vg * ld + koff + ((slot ^ (row & 7)) << 3);
      GLOAD16(bph + so, &Xh_lds[buf][(size_t)c * 8]);
      GLOAD16(bpl + so, &Xl_lds[buf][(size_t)c * 8]);
    }
    int ktb = (kt < Kw) ? (kt >> 6) : ((kt - Kw) >> 6);
    const unsigned short* mh = (kt < Kw) ? w0h : w1h;
    const unsigned short* ml = (kt < Kw) ? w0l : w1l;
#pragma unroll
    for (int i = 0; i < 2; ++i) {
      int c = tid + i * 512;           // 0..1023
      int half = c >> 9, ci = c & 511;
      size_t tb = ((size_t)((2 * colblk + half) * nktbw + ktb)) * 4096 + (size_t)ci * 8;
      GLOAD16(mh + tb, &Wh_lds[buf][half * 4096 + ci * 8]);
      GLOAD16(ml + tb, &Wl_lds[buf][half * 4096 + ci * 8]);
    }
  };

  auto COMPUTE = [&](int buf) {
#pragma unroll
    for (int ks = 0; ks < 2; ++ks) {
      int slot = ks * 4 + (lane >> 4);
      bf16x8 ah[4], al[4];
#pragma unroll
      for (int m = 0; m < 4; ++m) {
        int row = wm * 64 + m * 16 + (lane & 15);
        int off = SWZ(row, slot);
        ah[m] = *(const bf16x8*)&Xh_lds[buf][off];
        al[m] = *(const bf16x8*)&Xl_lds[buf][off];
      }
      bf16x8 bh[2], bl[2];
#pragma unroll
      for (int n = 0; n < 2; ++n) {
        int nr = wn * 32 + n * 16 + (lane & 15);   // 0..127
        int off = (nr >> 6) * 4096 + SWZ(nr & 63, slot);
        bh[n] = *(const bf16x8*)&Wh_lds[buf][off];
        bl[n] = *(const bf16x8*)&Wl_lds[buf][off];
      }
#pragma unroll
      for (int m = 0; m < 4; ++m)
#pragma unroll
        for (int n = 0; n < 2; ++n) {
          f32x4 c = acc[m][n];
          c = __builtin_amdgcn_mfma_f32_16x16x32_bf16(al[m], bh[n], c, 0, 0, 0);
          c = __builtin_amdgcn_mfma_f32_16x16x32_bf16(ah[m], bl[n], c, 0, 0, 0);
          c = __builtin_amdgcn_mfma_f32_16x16x32_bf16(ah[m], bh[n], c, 0, 0, 0);
          acc[m][n] = c;
        }
    }
  };

  // T3+T4 pipeline: prefetch tile t+1, wait COUNTED vmcnt(8) so the 8
  // just-issued loads stay in flight across the barrier; per-wave vmcnt +
  // barrier => all waves' tile-t loads are visible (m201 trick).
  int nt = Kmm >> 6;
  STAGE(0, 0);
  asm volatile("s_waitcnt vmcnt(0)" ::: "memory");
  __builtin_amdgcn_s_barrier();
  int buf = 0;
  for (int t = 0; t < nt; ++t) {
    if (t + 1 < nt) {
      STAGE(buf ^ 1, (t + 1) << 6);
      asm volatile("s_waitcnt vmcnt(8)" ::: "memory");
    } else {
      asm volatile("s_waitcnt vmcnt(0)" ::: "memory");
    }
    __builtin_amdgcn_s_barrier();
    __builtin_amdgcn_s_setprio(1);
    COMPUTE(buf);
    __builtin_amdgcn_s_setprio(0);
    asm volatile("s_waitcnt lgkmcnt(0)" ::: "memory");
    __builtin_amdgcn_s_barrier();   // all reads of buf done before next STAGE hits it
    buf ^= 1;
  }

  // epilogue: split( v + b0[col] + deg[row]*b1[col] ) into hi/lo planes
#pragma unroll
  for (int m = 0; m < 4; ++m) {
    int rbase = row0 + wm * 64 + m * 16 + (lane >> 4) * 4;
    float dv[4];
#pragma unroll
    for (int r = 0; r < 4; ++r)
      dv[r] = (rbase + r < N) ? (float)deg[rbase + r] : 0.f;
#pragma unroll
    for (int n = 0; n < 2; ++n) {
      int col = col0 + wn * 32 + n * 16 + (lane & 15);
      float bb0 = b0[col], bb1 = b1[col];
      f32x4 v = acc[m][n];
#pragma unroll
      for (int r = 0; r < 4; ++r) {
        int row = rbase + r;
        if (row < N) {
          unsigned short h, l;
          fsplit(v[r] + bb0 + dv[r] * bb1, h, l);
          Yh[(size_t)row * HID + col] = h;
          Yl[(size_t)row * HID + col] = l;
        }
      }
    }
  }
}

// Both 256x3 output heads in one X pass.
__global__ __launch_bounds__(256) void k_rowdot6(const unsigned short* __restrict__ Xh,
                                                 const unsigned short* __restrict__ Xl,
                                                 const float* __restrict__ W,
                                                 const float* __restrict__ b,
                                                 float* __restrict__ Y0,
                                                 float* __restrict__ Y1, int N) {
  int gid = blockIdx.x * blockDim.x + threadIdx.x;
  int row = gid >> 6;
  int lane = threadIdx.x & 63;
  if (row >= N) return;
  size_t base = (size_t)row * HID + lane * 4;
  us4 hv = *(const us4*)(Xh + base);
  us4 lv = *(const us4*)(Xl + base);
  float s[6] = {0.f, 0.f, 0.f, 0.f, 0.f, 0.f};
#pragma unroll
  for (int k = 0; k < 4; ++k) {
    float x = b2f(hv[k]) + b2f(lv[k]);
    int kk = lane * 4 + k;
#pragma unroll
    for (int j = 0; j < 3; ++j) {
      s[j]     += x * W[kk * 3 + j];
      s[3 + j] += x * W[768 + kk * 3 + j];
    }
  }
#pragma unroll
  for (int off = 32; off > 0; off >>= 1)
#pragma unroll
    for (int j = 0; j < 6; ++j) s[j] += __shfl_down(s[j], off);
  if (lane == 0) {
#pragma unroll
    for (int j = 0; j < 3; ++j) {
      Y0[(size_t)row * 3 + j] = s[j] + b[j];
      Y1[(size_t)row * 3 + j] = s[3 + j] + b[3 + j];
    }
  }
}

__global__ __launch_bounds__(256) void k_scatter3(const int* __restrict__ edges,
                                                  const float* __restrict__ H,
                                                  float* __restrict__ OUT, int E) {
  int e = blockIdx.x * blockDim.x + threadIdx.x;
  if (e >= E) return;
  int a = edges[(size_t)e * 2 + 0];
  int b = edges[(size_t)e * 2 + 1];
#pragma unroll
  for (int k = 0; k < 3; ++k) {
    atomicAdd(&OUT[(size_t)a * 3 + k], H[(size_t)b * 3 + k]);
    atomicAdd(&OUT[(size_t)b * 3 + k], H[(size_t)a * 3 + k]);
  }
}

__global__ __launch_bounds__(256) void k_subdiv3(const float* __restrict__ c,
                                                 const int* __restrict__ edges,
                                                 float* __restrict__ v, int N, int E) {
  int i = blockIdx.x * blockDim.x + threadIdx.x;
  if (i >= N + E) return;
  if (i < N) {
#pragma unroll
    for (int k = 0; k < 3; ++k) v[(size_t)i * 3 + k] = c[(size_t)i * 3 + k];
  } else {
    int e = i - N;
    int a = edges[(size_t)e * 2 + 0];
    int b = edges[(size_t)e * 2 + 1];
#pragma unroll
    for (int k = 0; k < 3; ++k)
      v[(size_t)i * 3 + k] = 0.5f * (c[(size_t)a * 3 + k] + c[(size_t)b * 3 + k]);
  }
}

// hs = subdiv(x): 8 channels/thread on hi/lo planes
__global__ __launch_bounds__(256) void k_subdiv_feat(const unsigned short* __restrict__ xh,
                                                     const unsigned short* __restrict__ xl,
                                                     const int* __restrict__ edges,
                                                     unsigned short* __restrict__ oh,
                                                     unsigned short* __restrict__ ol,
                                                     int N, int E) {
  int idx = blockIdx.x * blockDim.x + threadIdx.x;
  int v = idx >> 5;
  if (v >= N + E) return;
  int c = (idx & 31) * 8;
  us8 rh, rl;
  if (v < N) {
    rh = *(const us8*)(xh + (size_t)v * HID + c);
    rl = *(const us8*)(xl + (size_t)v * HID + c);
  } else {
    int e = v - N;
    int a = edges[(size_t)e * 2 + 0];
    int b = edges[(size_t)e * 2 + 1];
    us8 ahv = *(const us8*)(xh + (size_t)a * HID + c);
    us8 alv = *(const us8*)(xl + (size_t)a * HID + c);
    us8 bhv = *(const us8*)(xh + (size_t)b * HID + c);
    us8 blv = *(const us8*)(xl + (size_t)b * HID + c);
#pragma unroll
    for (int j = 0; j < 8; ++j) {
      float f = 0.5f * ((b2f(ahv[j]) + b2f(alv[j])) + (b2f(bhv[j]) + b2f(blv[j])));
      unsigned short hh, ll;
      fsplit(f, hh, ll);
      rh[j] = hh;
      rl[j] = ll;
    }
  }
  *(us8*)(oh + (size_t)v * HID + c) = rh;
  *(us8*)(ol + (size_t)v * HID + c) = rl;
}

// ---------------- launcher ----------------

extern "C" void kernel_launch(void* const* d_in, const int* in_sizes, int n_in,
                              void* d_out, int out_size, void* d_ws, size_t ws_size,
                              hipStream_t stream) {
  const float* conv64  = (const float*)d_in[0];
  const float* conv128 = (const float*)d_in[1];
  const float* conv256 = (const float*)d_in[2];
  const float* verts0  = (const float*)d_in[3];
  const int*   edges1  = (const int*)d_in[4];
  const int*   edges2  = (const int*)d_in[5];
  const int*   edges3  = (const int*)d_in[6];
  const float* w_in1 = (const float*)d_in[7],  *b_in1 = (const float*)d_in[8];
  const float* w_h1  = (const float*)d_in[9],  *b_h1  = (const float*)d_in[10];
  const float* w_out1= (const float*)d_in[11], *b_out1= (const float*)d_in[12];
  const float* w_in2 = (const float*)d_in[13], *b_in2 = (const float*)d_in[14];
  const float* w_h2  = (const float*)d_in[15], *b_h2  = (const float*)d_in[16];
  const float* w_out2= (const float*)d_in[17], *b_out2= (const float*)d_in[18];
  const float* w_in3 = (const float*)d_in[19], *b_in3 = (const float*)d_in[20];
  const float* w_h3  = (const float*)d_in[21], *b_h3  = (const float*)d_in[22];
  const float* w_out3= (const float*)d_in[23], *b_out3= (const float*)d_in[24];

  const int N1 = in_sizes[3] / 3;
  const int E1 = in_sizes[4] / 2;
  const int E2 = in_sizes[5] / 2;
  const int E3 = in_sizes[6] / 2;
  const int N2 = N1 + E1;
  const int N3 = N2 + E2;
  if ((size_t)N3 > MAXN3 || (size_t)E3 > MAXE3) return;

  unsigned short *Ah, *Al, *Bh, *Bl, *Gh, *Gl, *Dh, *Dl, *VAh, *VAl;
  float *C0, *C2, *Vv, *T;
  unsigned short *Wth, *Wtl;
  int *deg, *rowptr, *cursor, *adj, *bsum;
  hipGetSymbolAddress((void**)&Ah,  HIP_SYMBOL(g_Ah));
  hipGetSymbolAddress((void**)&Al,  HIP_SYMBOL(g_Al));
  hipGetSymbolAddress((void**)&Bh,  HIP_SYMBOL(g_Bh));
  hipGetSymbolAddress((void**)&Bl,  HIP_SYMBOL(g_Bl));
  hipGetSymbolAddress((void**)&Gh,  HIP_SYMBOL(g_Gh));
  hipGetSymbolAddress((void**)&Gl,  HIP_SYMBOL(g_Gl));
  hipGetSymbolAddress((void**)&Dh,  HIP_SYMBOL(g_Dh));
  hipGetSymbolAddress((void**)&Dl,  HIP_SYMBOL(g_Dl));
  hipGetSymbolAddress((void**)&VAh, HIP_SYMBOL(g_VAh));
  hipGetSymbolAddress((void**)&VAl, HIP_SYMBOL(g_VAl));
  hipGetSymbolAddress((void**)&C0, HIP_SYMBOL(g_C0));
  hipGetSymbolAddress((void**)&C2, HIP_SYMBOL(g_C2));
  hipGetSymbolAddress((void**)&Vv, HIP_SYMBOL(g_Vv));
  hipGetSymbolAddress((void**)&T,  HIP_SYMBOL(g_T));
  hipGetSymbolAddress((void**)&Wth, HIP_SYMBOL(g_Wth));
  hipGetSymbolAddress((void**)&Wtl, HIP_SYMBOL(g_Wtl));
  hipGetSymbolAddress((void**)&deg,    HIP_SYMBOL(g_deg));
  hipGetSymbolAddress((void**)&rowptr, HIP_SYMBOL(g_rowptr));
  hipGetSymbolAddress((void**)&cursor, HIP_SYMBOL(g_cursor));
  hipGetSymbolAddress((void**)&adj,    HIP_SYMBOL(g_adj));
  hipGetSymbolAddress((void**)&bsum,   HIP_SYMBOL(g_bsum));

  // ---- weight transpose + split + BK=64 tile-swizzle (once per launch) ----
  k_wtrans<<<dim3(2, 4, 2),  256, 0, stream>>>(w_in1, Wth + OFF_IN1, Wtl + OFF_IN1, 128);
  k_wtrans<<<dim3(6, 4, 2),  256, 0, stream>>>(w_in2, Wth + OFF_IN2, Wtl + OFF_IN2, 384);
  k_wtrans<<<dim3(6, 4, 2),  256, 0, stream>>>(w_in3, Wth + OFF_IN3, Wtl + OFF_IN3, 384);
  k_wtrans<<<dim3(4, 4, 24), 256, 0, stream>>>(w_h1,  Wth + OFF_H1,  Wtl + OFF_H1,  256);
  k_wtrans<<<dim3(4, 4, 24), 256, 0, stream>>>(w_h2,  Wth + OFF_H2,  Wtl + OFF_H2,  256);
  k_wtrans<<<dim3(4, 4, 24), 256, 0, stream>>>(w_h3,  Wth + OFF_H3,  Wtl + OFF_H3,  256);

  const int BIG = 0x7fffffff;

  auto layerGrid = [](int N) { return dim3((unsigned)(((N + 127) / 128) * 2)); };

  auto build_csr = [&](const int* edges, int E, int N) {
    hipMemsetAsync(deg, 0, (size_t)N * sizeof(int), stream);
    k_count<<<(E + 255) / 256, 256, 0, stream>>>(edges, deg, E);
    int nb = (N + 1023) / 1024;
    k_scan_part<<<nb, 256, 0, stream>>>(deg, bsum, N);
    k_scan_top<<<1, 128, 0, stream>>>(bsum, nb);
    k_scan_write<<<nb, 256, 0, stream>>>(deg, bsum, rowptr, cursor, N);
    k_fill<<<(E + 255) / 256, 256, 0, stream>>>(edges, cursor, adj, E);
  };

  auto gconv_hidden = [&](size_t offH, const float* bh, int N) {
    unsigned short *Xh = Ah, *Xl = Al, *Yh = Bh, *Yl = Bl;
    for (int l = 0; l < 12; ++l) {
      const unsigned short* w0h = Wth + offH + (size_t)(2 * l + 0) * 65536;
      const unsigned short* w0l = Wtl + offH + (size_t)(2 * l + 0) * 65536;
      const unsigned short* w1h = Wth + offH + (size_t)(2 * l + 1) * 65536;
      const unsigned short* w1l = Wtl + offH + (size_t)(2 * l + 1) * 65536;
      const float* b0 = bh + (size_t)l * 2 * HID;
      const float* b1 = b0 + HID;
      k_gather<256><<<((size_t)N * 32 + 255) / 256, 256, 0, stream>>>(
          rowptr, adj, Xh, Xl, Gh, Gl, N);
      Panels pd = {{Xh, Gh, nullptr, nullptr}, {Xl, Gl, nullptr, nullptr},
                   {0, 256, BIG, BIG}, {256, 256, 0, 0}};
      k_layer<<<layerGrid(N), 512, 0, stream>>>(pd, 512, w0h, w0l, w1h, w1l, 256,
                                                b0, b1, deg, Yh, Yl, N);
      std::swap(Xh, Yh);
      std::swap(Xl, Yl);
    }
    // x ends in A planes (12 swaps)
  };

  auto gconv_out = [&](const unsigned short* Xh, const unsigned short* Xl,
                       const float* wo, const float* bo,
                       float* Cdst, const int* edges, int E, int N) {
    k_rowdot6<<<((size_t)N * 64 + 255) / 256, 256, 0, stream>>>(Xh, Xl, wo, bo, Cdst, C2, N);
    k_scatter3<<<(E + 255) / 256, 256, 0, stream>>>(edges, C2, Cdst, E);
  };

  // ---------- Stage 1 ----------
  build_csr(edges1, E1, N1);
  k_transpose<<<56 * 56, 128, 0, stream>>>(conv64, T, 56 * 56);
  k_vert_align<<<N1, 128, 0, stream>>>(T, verts0, VAh, VAl, N1, 56, 56);
  k_gather<128><<<((size_t)N1 * 16 + 255) / 256, 256, 0, stream>>>(
      rowptr, adj, VAh, VAl, Gh, Gl, N1);
  {
    Panels pd = {{VAh, Gh, nullptr, nullptr}, {VAl, Gl, nullptr, nullptr},
                 {0, 128, BIG, BIG}, {128, 128, 0, 0}};
    k_layer<<<layerGrid(N1), 512, 0, stream>>>(pd, 256,
        Wth + OFF_IN1, Wtl + OFF_IN1, Wth + OFF_IN1 + 32768, Wtl + OFF_IN1 + 32768, 128,
        b_in1, b_in1 + HID, deg, Ah, Al, N1);
  }
  gconv_hidden(OFF_H1, b_h1, N1);                          // x -> A planes
  gconv_out(Ah, Al, w_out1, b_out1, C0, edges1, E1, N1);   // c1 -> C0
  k_subdiv3<<<(N2 + 255) / 256, 256, 0, stream>>>(C0, edges1, Vv, N1, E1);  // v2
  k_subdiv_feat<<<((size_t)N2 * 32 + 255) / 256, 256, 0, stream>>>(
      Ah, Al, edges1, Dh, Dl, N1, E1);                                      // hs -> D

  // ---------- Stage 2 ----------
  build_csr(edges2, E2, N2);
  k_transpose<<<28 * 28, 128, 0, stream>>>(conv128, T, 28 * 28);
  k_vert_align<<<N2, 128, 0, stream>>>(T, Vv, VAh, VAl, N2, 28, 28);
  k_gather<128><<<((size_t)N2 * 16 + 255) / 256, 256, 0, stream>>>(
      rowptr, adj, VAh, VAl, Gh, Gl, N2);
  k_gather<256><<<((size_t)N2 * 32 + 255) / 256, 256, 0, stream>>>(
      rowptr, adj, Dh, Dl, Bh, Bl, N2);
  {
    const size_t m0 = OFF_IN2, m1 = OFF_IN2 + (size_t)256 * 384;
    Panels pd = {{VAh, Dh, Gh, Bh}, {VAl, Dl, Gl, Bl},
                 {0, 128, 384, 512}, {128, 256, 128, 256}};
    k_layer<<<layerGrid(N2), 512, 0, stream>>>(pd, 768,
        Wth + m0, Wtl + m0, Wth + m1, Wtl + m1, 384,
        b_in2, b_in2 + HID, deg, Ah, Al, N2);
  }
  gconv_hidden(OFF_H2, b_h2, N2);                          // x -> A planes
  gconv_out(Ah, Al, w_out2, b_out2, C0, edges2, E2, N2);   // c2 -> C0
  k_subdiv3<<<(N3 + 255) / 256, 256, 0, stream>>>(C0, edges2, Vv, N2, E2);  // v3
  k_subdiv_feat<<<((size_t)N3 * 32 + 255) / 256, 256, 0, stream>>>(
      Ah, Al, edges2, Dh, Dl, N2, E2);                                      // hs -> D

  // ---------- Stage 3 ----------
  build_csr(edges3, E3, N3);
  k_transpose<<<14 * 14, 128, 0, stream>>>(conv256, T, 14 * 14);
  k_vert_align<<<N3, 128, 0, stream>>>(T, Vv, VAh, VAl, N3, 14, 14);
  k_gather<128><<<((size_t)N3 * 16 + 255) / 256, 256, 0, stream>>>(
      rowptr, adj, VAh, VAl, Gh, Gl, N3);
  k_gather<256><<<((size_t)N3 * 32 + 255) / 256, 256, 0, stream>>>(
      rowptr, adj, Dh, Dl, Bh, Bl, N3);
  {
    const size_t m0 = OFF_IN3, m1 = OFF_IN3 + (size_t)256 * 384;
    Panels pd = {{VAh, Dh, Gh, Bh}, {VAl, Dl, Gl, Bl},
                 {0, 128, 384, 512}, {128, 256, 128, 256}};
    k_layer<<<layerGrid(N3), 512, 0, stream>>>(pd, 768,
        Wth + m0, Wtl + m0, Wth + m1, Wtl + m1, 384,
        b_in3, b_in3 + HID, deg, Ah, Al, N3);
  }
  gconv_hidden(OFF_H3, b_h3, N3);                          // x -> A planes
  float* OUT = (float*)d_out;
  k_rowdot6<<<((size_t)N3 * 64 + 255) / 256, 256, 0, stream>>>(
      Ah, Al, w_out3, b_out3, OUT, C2, N3);
  k_scatter3<<<(E3 + 255) / 256, 256, 0, stream>>>(edges3, C2, OUT, E3);
}

// Round 14
// 3904.972 us; speedup vs baseline: 1.2327x; 1.2327x over previous
//
#include <hip/hip_runtime.h>
#include <utility>

#define HID 256

typedef __attribute__((ext_vector_type(8))) short bf16x8;
typedef __attribute__((ext_vector_type(4))) float f32x4;
typedef __attribute__((ext_vector_type(4))) unsigned short us4;
typedef __attribute__((ext_vector_type(8))) unsigned short us8;

// Topology constants for GRID_N=80
constexpr size_t MAXN3 = 100489;
constexpr size_t MAXE3 = 300200;

// Tiled-weight offsets (elements). Per matrix: [4 cb][K/64 ktb][4096 bf16],
// tile content pre-swizzled so a LINEAR global_load_lds produces the swizzled image.
constexpr size_t OFF_IN1 = 0;                       // 2 mats K=128
constexpr size_t OFF_IN2 = OFF_IN1 + 2 * 256 * 128; // 2 mats K=384
constexpr size_t OFF_IN3 = OFF_IN2 + 2 * 256 * 384;
constexpr size_t OFF_H1  = OFF_IN3 + 2 * 256 * 384; // 24 mats K=256
constexpr size_t OFF_H2  = OFF_H1 + 24 * 256 * 256;
constexpr size_t OFF_H3  = OFF_H2 + 24 * 256 * 256;
constexpr size_t WT_TOTAL = OFF_H3 + 24 * 256 * 256;

// Static device scratch (BSS — graph-capture safe). Features = split bf16
// hi/lo PLANES: x == b2f(hi) + b2f(lo) exactly.
__device__ __attribute__((aligned(16))) unsigned short g_Ah[MAXN3 * 256];
__device__ __attribute__((aligned(16))) unsigned short g_Al[MAXN3 * 256];
__device__ __attribute__((aligned(16))) unsigned short g_Bh[MAXN3 * 256];
__device__ __attribute__((aligned(16))) unsigned short g_Bl[MAXN3 * 256];
__device__ __attribute__((aligned(16))) unsigned short g_Gh[MAXN3 * 256];
__device__ __attribute__((aligned(16))) unsigned short g_Gl[MAXN3 * 256];
__device__ __attribute__((aligned(16))) unsigned short g_Dh[MAXN3 * 256];
__device__ __attribute__((aligned(16))) unsigned short g_Dl[MAXN3 * 256];
__device__ __attribute__((aligned(16))) unsigned short g_VAh[MAXN3 * 128];
__device__ __attribute__((aligned(16))) unsigned short g_VAl[MAXN3 * 128];
__device__ float g_C0[MAXN3 * 3];
__device__ float g_C2[MAXN3 * 3];
__device__ float g_Vv[MAXN3 * 3];
__device__ float g_T [56 * 56 * 128];
__device__ __attribute__((aligned(16))) unsigned short g_Wth[WT_TOTAL];
__device__ __attribute__((aligned(16))) unsigned short g_Wtl[WT_TOTAL];
// CSR scratch
__device__ int g_deg   [MAXN3];
__device__ int g_rowptr[MAXN3 + 1];
__device__ int g_cursor[MAXN3];
__device__ int g_adj   [2 * MAXE3];
__device__ int g_bsum  [128];

__device__ inline float b2f(unsigned short h) {
  return __uint_as_float((unsigned)h << 16);
}
__device__ inline void fsplit(float f, unsigned short& h, unsigned short& l) {
  unsigned u = __float_as_uint(f);
  h = (unsigned short)(u >> 16);
  float hf = __uint_as_float(u & 0xffff0000u);
  l = (unsigned short)(__float_as_uint(f - hf) >> 16);
}

#define GLOAD16(g, l)                                                       \
  __builtin_amdgcn_global_load_lds(                                        \
      (const __attribute__((address_space(1))) unsigned*)(const void*)(g), \
      (__attribute__((address_space(3))) unsigned*)(void*)(l), 16, 0, 0)

// ---------------- weight transpose + split + tile-swizzle (BK=64 tiles) ----------------
// Out tile chunk c (n=c>>3, sp=c&7) holds W^T[cb*64+n][ktb*64+(sp^(n&7))*8 .. +7]
__global__ __launch_bounds__(256) void k_wtrans(const float* __restrict__ W,
                                                unsigned short* __restrict__ Oh,
                                                unsigned short* __restrict__ Ol,
                                                int K) {
  __shared__ float Ls[64][65];
  int ktb = blockIdx.x, cb = blockIdx.y, mat = blockIdx.z;
  int nktb = gridDim.x;
  const float* Wm = W + (size_t)mat * K * 256;
  int t = threadIdx.x;
#pragma unroll
  for (int i = 0; i < 16; ++i) {
    int idx = i * 256 + t;
    int kk = idx >> 6, cc = idx & 63;
    Ls[kk][cc] = Wm[(size_t)(ktb * 64 + kk) * 256 + cb * 64 + cc];
  }
  __syncthreads();
  size_t tb = ((size_t)(mat * 4 + cb) * nktb + ktb) * 4096;
#pragma unroll
  for (int i = 0; i < 2; ++i) {
    int c = t * 2 + i;
    int n = c >> 3, sp = c & 7;
    int kbase = (sp ^ (n & 7)) * 8;
    unsigned short hb[8], lb[8];
#pragma unroll
    for (int j = 0; j < 8; ++j) {
      float v = Ls[kbase + j][n];
      unsigned short hi, lo;
      fsplit(v, hi, lo);
      hb[j] = hi;
      lb[j] = lo;
    }
    *(us4*)(Oh + tb + c * 8)     = (us4){hb[0], hb[1], hb[2], hb[3]};
    *(us4*)(Oh + tb + c * 8 + 4) = (us4){hb[4], hb[5], hb[6], hb[7]};
    *(us4*)(Ol + tb + c * 8)     = (us4){lb[0], lb[1], lb[2], lb[3]};
    *(us4*)(Ol + tb + c * 8 + 4) = (us4){lb[4], lb[5], lb[6], lb[7]};
  }
}

// ---------------- CSR build (parallel scan) ----------------

__global__ __launch_bounds__(256) void k_count(const int* __restrict__ edges,
                                               int* __restrict__ deg, int E) {
  int e = blockIdx.x * blockDim.x + threadIdx.x;
  if (e >= E) return;
  atomicAdd(&deg[edges[2 * e + 0]], 1);
  atomicAdd(&deg[edges[2 * e + 1]], 1);
}

__global__ __launch_bounds__(256) void k_scan_part(const int* __restrict__ deg,
                                                   int* __restrict__ bsum, int N) {
  __shared__ int s[256];
  int t = threadIdx.x;
  int base = blockIdx.x * 1024 + t * 4;
  int v = 0;
#pragma unroll
  for (int i = 0; i < 4; ++i) {
    int idx = base + i;
    if (idx < N) v += deg[idx];
  }
  s[t] = v;
  __syncthreads();
  for (int off = 128; off > 0; off >>= 1) {
    if (t < off) s[t] += s[t + off];
    __syncthreads();
  }
  if (t == 0) bsum[blockIdx.x] = s[0];
}

__global__ __launch_bounds__(128) void k_scan_top(int* __restrict__ bsum, int nb) {
  __shared__ int s[128];
  int t = threadIdx.x;
  s[t] = (t < nb) ? bsum[t] : 0;
  __syncthreads();
  for (int off = 1; off < 128; off <<= 1) {
    int v = (t >= off) ? s[t - off] : 0;
    __syncthreads();
    s[t] += v;
    __syncthreads();
  }
  if (t < nb) bsum[t] = (t == 0) ? 0 : s[t - 1];
}

__global__ __launch_bounds__(256) void k_scan_write(const int* __restrict__ deg,
                                                    const int* __restrict__ bsum,
                                                    int* __restrict__ rowptr,
                                                    int* __restrict__ cursor, int N) {
  __shared__ int s[256];
  int t = threadIdx.x;
  int base = blockIdx.x * 1024;
  int d[4];
  int local = 0;
#pragma unroll
  for (int i = 0; i < 4; ++i) {
    int idx = base + t * 4 + i;
    d[i] = (idx < N) ? deg[idx] : 0;
    local += d[i];
  }
  s[t] = local;
  __syncthreads();
  for (int off = 1; off < 256; off <<= 1) {
    int v = (t >= off) ? s[t - off] : 0;
    __syncthreads();
    s[t] += v;
    __syncthreads();
  }
  int run = bsum[blockIdx.x] + s[t] - local;
#pragma unroll
  for (int i = 0; i < 4; ++i) {
    int idx = base + t * 4 + i;
    if (idx < N) {
      rowptr[idx] = run;
      cursor[idx] = run;
    }
    run += d[i];
  }
  if (blockIdx.x == gridDim.x - 1 && t == 255) rowptr[N] = run;
}

__global__ __launch_bounds__(256) void k_fill(const int* __restrict__ edges,
                                              int* __restrict__ cursor,
                                              int* __restrict__ adj, int E) {
  int e = blockIdx.x * blockDim.x + threadIdx.x;
  if (e >= E) return;
  int a = edges[2 * e + 0];
  int b = edges[2 * e + 1];
  adj[atomicAdd(&cursor[a], 1)] = b;
  adj[atomicAdd(&cursor[b], 1)] = a;
}

// ---------------- misc kernels ----------------

__global__ __launch_bounds__(128) void k_transpose(const float* __restrict__ in,
                                                   float* __restrict__ out, int HW) {
  int p = blockIdx.x;
  int c = threadIdx.x;
  if (p < HW) out[(size_t)p * 128 + c] = in[(size_t)c * HW + p];
}

__global__ __launch_bounds__(128) void k_vert_align(const float* __restrict__ fT,
                                                    const float* __restrict__ verts,
                                                    unsigned short* __restrict__ oh,
                                                    unsigned short* __restrict__ ol,
                                                    int N, int H, int W) {
  int v = blockIdx.x;
  if (v >= N) return;
  int c = threadIdx.x;
  float vx = verts[(size_t)v * 3 + 0];
  float vy = verts[(size_t)v * 3 + 1];
  float fx = (vx + 1.f) * 0.5f * (float)(W - 1);
  float fy = (vy + 1.f) * 0.5f * (float)(H - 1);
  float x0f = floorf(fx), y0f = floorf(fy);
  float wx = fx - x0f, wy = fy - y0f;
  int x0 = (int)x0f, y0 = (int)y0f;
  float acc = 0.f;
#pragma unroll
  for (int dy = 0; dy < 2; ++dy) {
#pragma unroll
    for (int dx = 0; dx < 2; ++dx) {
      int yi = y0 + dy, xi = x0 + dx;
      bool valid = (yi >= 0) && (yi < H) && (xi >= 0) && (xi < W);
      int yc = min(max(yi, 0), H - 1);
      int xc = min(max(xi, 0), W - 1);
      float val = fT[((size_t)yc * W + xc) * 128 + c];
      float wgt = (dy ? wy : 1.f - wy) * (dx ? wx : 1.f - wx);
      acc += valid ? val * wgt : 0.f;
    }
  }
  unsigned short h, l;
  fsplit(acc, h, l);
  oh[(size_t)v * 128 + c] = h;
  ol[(size_t)v * 128 + c] = l;
}

// G[v] = split( sum_{u in adj(v)} (b2f(Xh[u]) + b2f(Xl[u])) ), 8 ch/thread
template <int CH>
__global__ __launch_bounds__(256) void k_gather(const int* __restrict__ rowptr,
                                                const int* __restrict__ adj,
                                                const unsigned short* __restrict__ Xh,
                                                const unsigned short* __restrict__ Xl,
                                                unsigned short* __restrict__ Gh,
                                                unsigned short* __restrict__ Gl, int N) {
  constexpr int TPV = CH / 8;
  int idx = blockIdx.x * blockDim.x + threadIdx.x;
  int v = idx / TPV;
  if (v >= N) return;
  int c = (idx % TPV) * 8;
  float a[8] = {};
  int lo = rowptr[v], hi = rowptr[v + 1];
  for (int i = lo; i < hi; ++i) {
    size_t base = (size_t)adj[i] * CH + c;
    us8 h = *(const us8*)(Xh + base);
    us8 l = *(const us8*)(Xl + base);
#pragma unroll
    for (int j = 0; j < 8; ++j) a[j] += b2f(h[j]) + b2f(l[j]);
  }
  us8 oh, ol;
#pragma unroll
  for (int j = 0; j < 8; ++j) {
    unsigned short hh, ll;
    fsplit(a[j], hh, ll);
    oh[j] = hh;
    ol[j] = ll;
  }
  *(us8*)(Gh + (size_t)v * CH + c) = oh;
  *(us8*)(Gl + (size_t)v * CH + c) = ol;
}

// ---- split-plane MFMA layer (128x128 tile, BK=64, single-buffer, 8 waves) ----
struct Panels {
  const unsigned short* ph[4];
  const unsigned short* pl[4];
  int ks[4];
  int ld[4];
};

// involution swizzle: LDS[row][s] holds source chunk s^(row&7); 8-bf16 chunks
#define SWZ(row, slot) (((row) * 64) + (((slot) ^ ((row) & 7)) << 3))

__global__ __launch_bounds__(512, 2) void k_layer(
    Panels pd, int Kmm,
    const unsigned short* __restrict__ w0h, const unsigned short* __restrict__ w0l,
    const unsigned short* __restrict__ w1h, const unsigned short* __restrict__ w1l,
    int Kw,
    const float* __restrict__ b0, const float* __restrict__ b1,
    const int* __restrict__ deg,
    unsigned short* __restrict__ Yh, unsigned short* __restrict__ Yl, int N) {
  // 64 KB total -> 2 blocks/CU x 8 waves = 16 waves/CU
  __shared__ __attribute__((aligned(16))) unsigned short Xh_lds[128 * 64]; // 16 KB
  __shared__ __attribute__((aligned(16))) unsigned short Xl_lds[128 * 64]; // 16 KB
  __shared__ __attribute__((aligned(16))) unsigned short Wh_lds[2 * 4096]; // 16 KB
  __shared__ __attribute__((aligned(16))) unsigned short Wl_lds[2 * 4096]; // 16 KB
  int tid = threadIdx.x;
  int lane = tid & 63;
  int wid = tid >> 6;          // 0..7
  int wm = wid >> 2;           // 0..1 (64-row half)
  int wn = wid & 3;            // 0..3 (32-col group)

  // XCD-aware swizzle: groups of 8 row-tiles x 2 col-blocks
  int nrt = (N + 127) >> 7;
  int total = nrt * 2;
  int flat = blockIdx.x;
  int rowtile, colblk;
  if ((flat & ~15) + 16 <= total) {
    int sub = flat & 15;
    rowtile = (flat >> 4) * 8 + (sub & 7);
    colblk = sub >> 3;
  } else {
    rowtile = flat >> 1;
    colblk = flat & 1;
  }
  int row0 = rowtile * 128;
  int col0 = colblk * 128;
  int nktbw = Kw >> 6;

  f32x4 acc[4][2];
#pragma unroll
  for (int m = 0; m < 4; ++m)
#pragma unroll
    for (int n = 0; n < 2; ++n) acc[m][n] = (f32x4){0.f, 0.f, 0.f, 0.f};

  for (int kt = 0; kt < Kmm; kt += 64) {
    int pi = (kt >= pd.ks[1]) + (kt >= pd.ks[2]) + (kt >= pd.ks[3]);
    const unsigned short* bph = pd.ph[pi];
    const unsigned short* bpl = pd.pl[pi];
    int ld = pd.ld[pi];
    int koff = kt - pd.ks[pi];
    // ---- X stage: 1024 16B-chunks per plane; chunk c: row=c>>3, slot=c&7;
    //      source pre-swizzled chunk = slot^(row&7); LDS linear.
#pragma unroll
    for (int i = 0; i < 2; ++i) {
      int c = tid + i * 512;
      int row = c >> 3, slot = c & 7;
      int vg = min(row0 + row, N - 1);
      size_t so = (size_t)vg * ld + koff + ((slot ^ (row & 7)) << 3);
      GLOAD16(bph + so, &Xh_lds[(size_t)c * 8]);
      GLOAD16(bpl + so, &Xl_lds[(size_t)c * 8]);
    }
    // ---- W stage: two 64-col pre-swizzled tiles per plane, linear DMA
    {
      int ktb = (kt < Kw) ? (kt >> 6) : ((kt - Kw) >> 6);
      const unsigned short* mh = (kt < Kw) ? w0h : w1h;
      const unsigned short* ml = (kt < Kw) ? w0l : w1l;
#pragma unroll
      for (int i = 0; i < 2; ++i) {
        int c = tid + i * 512;           // 0..1023
        int half = c >> 9, ci = c & 511;
        size_t tb = ((size_t)((2 * colblk + half) * nktbw + ktb)) * 4096 + (size_t)ci * 8;
        GLOAD16(mh + tb, &Wh_lds[half * 4096 + ci * 8]);
        GLOAD16(ml + tb, &Wl_lds[half * 4096 + ci * 8]);
      }
    }
    __syncthreads();
    // ---- compute: per ks read 8 A + 4 B (b128), 24 MFMA per wave
#pragma unroll
    for (int ks = 0; ks < 2; ++ks) {
      int slot = ks * 4 + (lane >> 4);
      bf16x8 ah[4], al[4];
#pragma unroll
      for (int m = 0; m < 4; ++m) {
        int row = wm * 64 + m * 16 + (lane & 15);
        int off = SWZ(row, slot);
        ah[m] = *(const bf16x8*)&Xh_lds[off];
        al[m] = *(const bf16x8*)&Xl_lds[off];
      }
      bf16x8 bh[2], bl[2];
#pragma unroll
      for (int n = 0; n < 2; ++n) {
        int nr = wn * 32 + n * 16 + (lane & 15);   // 0..127
        int off = (nr >> 6) * 4096 + SWZ(nr & 63, slot);
        bh[n] = *(const bf16x8*)&Wh_lds[off];
        bl[n] = *(const bf16x8*)&Wl_lds[off];
      }
#pragma unroll
      for (int m = 0; m < 4; ++m)
#pragma unroll
        for (int n = 0; n < 2; ++n) {
          f32x4 c = acc[m][n];
          c = __builtin_amdgcn_mfma_f32_16x16x32_bf16(al[m], bh[n], c, 0, 0, 0);
          c = __builtin_amdgcn_mfma_f32_16x16x32_bf16(ah[m], bl[n], c, 0, 0, 0);
          c = __builtin_amdgcn_mfma_f32_16x16x32_bf16(ah[m], bh[n], c, 0, 0, 0);
          acc[m][n] = c;
        }
    }
    __syncthreads();
  }

  // epilogue: split( v + b0[col] + deg[row]*b1[col] ) into hi/lo planes
#pragma unroll
  for (int m = 0; m < 4; ++m) {
    int rbase = row0 + wm * 64 + m * 16 + (lane >> 4) * 4;
    float dv[4];
#pragma unroll
    for (int r = 0; r < 4; ++r)
      dv[r] = (rbase + r < N) ? (float)deg[rbase + r] : 0.f;
#pragma unroll
    for (int n = 0; n < 2; ++n) {
      int col = col0 + wn * 32 + n * 16 + (lane & 15);
      float bb0 = b0[col], bb1 = b1[col];
      f32x4 v = acc[m][n];
#pragma unroll
      for (int r = 0; r < 4; ++r) {
        int row = rbase + r;
        if (row < N) {
          unsigned short h, l;
          fsplit(v[r] + bb0 + dv[r] * bb1, h, l);
          Yh[(size_t)row * HID + col] = h;
          Yl[(size_t)row * HID + col] = l;
        }
      }
    }
  }
}

// Both 256x3 output heads in one X pass.
__global__ __launch_bounds__(256) void k_rowdot6(const unsigned short* __restrict__ Xh,
                                                 const unsigned short* __restrict__ Xl,
                                                 const float* __restrict__ W,
                                                 const float* __restrict__ b,
                                                 float* __restrict__ Y0,
                                                 float* __restrict__ Y1, int N) {
  int gid = blockIdx.x * blockDim.x + threadIdx.x;
  int row = gid >> 6;
  int lane = threadIdx.x & 63;
  if (row >= N) return;
  size_t base = (size_t)row * HID + lane * 4;
  us4 hv = *(const us4*)(Xh + base);
  us4 lv = *(const us4*)(Xl + base);
  float s[6] = {0.f, 0.f, 0.f, 0.f, 0.f, 0.f};
#pragma unroll
  for (int k = 0; k < 4; ++k) {
    float x = b2f(hv[k]) + b2f(lv[k]);
    int kk = lane * 4 + k;
#pragma unroll
    for (int j = 0; j < 3; ++j) {
      s[j]     += x * W[kk * 3 + j];
      s[3 + j] += x * W[768 + kk * 3 + j];
    }
  }
#pragma unroll
  for (int off = 32; off > 0; off >>= 1)
#pragma unroll
    for (int j = 0; j < 6; ++j) s[j] += __shfl_down(s[j], off);
  if (lane == 0) {
#pragma unroll
    for (int j = 0; j < 3; ++j) {
      Y0[(size_t)row * 3 + j] = s[j] + b[j];
      Y1[(size_t)row * 3 + j] = s[3 + j] + b[3 + j];
    }
  }
}

__global__ __launch_bounds__(256) void k_scatter3(const int* __restrict__ edges,
                                                  const float* __restrict__ H,
                                                  float* __restrict__ OUT, int E) {
  int e = blockIdx.x * blockDim.x + threadIdx.x;
  if (e >= E) return;
  int a = edges[(size_t)e * 2 + 0];
  int b = edges[(size_t)e * 2 + 1];
#pragma unroll
  for (int k = 0; k < 3; ++k) {
    atomicAdd(&OUT[(size_t)a * 3 + k], H[(size_t)b * 3 + k]);
    atomicAdd(&OUT[(size_t)b * 3 + k], H[(size_t)a * 3 + k]);
  }
}

__global__ __launch_bounds__(256) void k_subdiv3(const float* __restrict__ c,
                                                 const int* __restrict__ edges,
                                                 float* __restrict__ v, int N, int E) {
  int i = blockIdx.x * blockDim.x + threadIdx.x;
  if (i >= N + E) return;
  if (i < N) {
#pragma unroll
    for (int k = 0; k < 3; ++k) v[(size_t)i * 3 + k] = c[(size_t)i * 3 + k];
  } else {
    int e = i - N;
    int a = edges[(size_t)e * 2 + 0];
    int b = edges[(size_t)e * 2 + 1];
#pragma unroll
    for (int k = 0; k < 3; ++k)
      v[(size_t)i * 3 + k] = 0.5f * (c[(size_t)a * 3 + k] + c[(size_t)b * 3 + k]);
  }
}

// hs = subdiv(x): 8 channels/thread on hi/lo planes
__global__ __launch_bounds__(256) void k_subdiv_feat(const unsigned short* __restrict__ xh,
                                                     const unsigned short* __restrict__ xl,
                                                     const int* __restrict__ edges,
                                                     unsigned short* __restrict__ oh,
                                                     unsigned short* __restrict__ ol,
                                                     int N, int E) {
  int idx = blockIdx.x * blockDim.x + threadIdx.x;
  int v = idx >> 5;
  if (v >= N + E) return;
  int c = (idx & 31) * 8;
  us8 rh, rl;
  if (v < N) {
    rh = *(const us8*)(xh + (size_t)v * HID + c);
    rl = *(const us8*)(xl + (size_t)v * HID + c);
  } else {
    int e = v - N;
    int a = edges[(size_t)e * 2 + 0];
    int b = edges[(size_t)e * 2 + 1];
    us8 ahv = *(const us8*)(xh + (size_t)a * HID + c);
    us8 alv = *(const us8*)(xl + (size_t)a * HID + c);
    us8 bhv = *(const us8*)(xh + (size_t)b * HID + c);
    us8 blv = *(const us8*)(xl + (size_t)b * HID + c);
#pragma unroll
    for (int j = 0; j < 8; ++j) {
      float f = 0.5f * ((b2f(ahv[j]) + b2f(alv[j])) + (b2f(bhv[j]) + b2f(blv[j])));
      unsigned short hh, ll;
      fsplit(f, hh, ll);
      rh[j] = hh;
      rl[j] = ll;
    }
  }
  *(us8*)(oh + (size_t)v * HID + c) = rh;
  *(us8*)(ol + (size_t)v * HID + c) = rl;
}

// ---------------- launcher ----------------

extern "C" void kernel_launch(void* const* d_in, const int* in_sizes, int n_in,
                              void* d_out, int out_size, void* d_ws, size_t ws_size,
                              hipStream_t stream) {
  const float* conv64  = (const float*)d_in[0];
  const float* conv128 = (const float*)d_in[1];
  const float* conv256 = (const float*)d_in[2];
  const float* verts0  = (const float*)d_in[3];
  const int*   edges1  = (const int*)d_in[4];
  const int*   edges2  = (const int*)d_in[5];
  const int*   edges3  = (const int*)d_in[6];
  const float* w_in1 = (const float*)d_in[7],  *b_in1 = (const float*)d_in[8];
  const float* w_h1  = (const float*)d_in[9],  *b_h1  = (const float*)d_in[10];
  const float* w_out1= (const float*)d_in[11], *b_out1= (const float*)d_in[12];
  const float* w_in2 = (const float*)d_in[13], *b_in2 = (const float*)d_in[14];
  const float* w_h2  = (const float*)d_in[15], *b_h2  = (const float*)d_in[16];
  const float* w_out2= (const float*)d_in[17], *b_out2= (const float*)d_in[18];
  const float* w_in3 = (const float*)d_in[19], *b_in3 = (const float*)d_in[20];
  const float* w_h3  = (const float*)d_in[21], *b_h3  = (const float*)d_in[22];
  const float* w_out3= (const float*)d_in[23], *b_out3= (const float*)d_in[24];

  const int N1 = in_sizes[3] / 3;
  const int E1 = in_sizes[4] / 2;
  const int E2 = in_sizes[5] / 2;
  const int E3 = in_sizes[6] / 2;
  const int N2 = N1 + E1;
  const int N3 = N2 + E2;
  if ((size_t)N3 > MAXN3 || (size_t)E3 > MAXE3) return;

  unsigned short *Ah, *Al, *Bh, *Bl, *Gh, *Gl, *Dh, *Dl, *VAh, *VAl;
  float *C0, *C2, *Vv, *T;
  unsigned short *Wth, *Wtl;
  int *deg, *rowptr, *cursor, *adj, *bsum;
  hipGetSymbolAddress((void**)&Ah,  HIP_SYMBOL(g_Ah));
  hipGetSymbolAddress((void**)&Al,  HIP_SYMBOL(g_Al));
  hipGetSymbolAddress((void**)&Bh,  HIP_SYMBOL(g_Bh));
  hipGetSymbolAddress((void**)&Bl,  HIP_SYMBOL(g_Bl));
  hipGetSymbolAddress((void**)&Gh,  HIP_SYMBOL(g_Gh));
  hipGetSymbolAddress((void**)&Gl,  HIP_SYMBOL(g_Gl));
  hipGetSymbolAddress((void**)&Dh,  HIP_SYMBOL(g_Dh));
  hipGetSymbolAddress((void**)&Dl,  HIP_SYMBOL(g_Dl));
  hipGetSymbolAddress((void**)&VAh, HIP_SYMBOL(g_VAh));
  hipGetSymbolAddress((void**)&VAl, HIP_SYMBOL(g_VAl));
  hipGetSymbolAddress((void**)&C0, HIP_SYMBOL(g_C0));
  hipGetSymbolAddress((void**)&C2, HIP_SYMBOL(g_C2));
  hipGetSymbolAddress((void**)&Vv, HIP_SYMBOL(g_Vv));
  hipGetSymbolAddress((void**)&T,  HIP_SYMBOL(g_T));
  hipGetSymbolAddress((void**)&Wth, HIP_SYMBOL(g_Wth));
  hipGetSymbolAddress((void**)&Wtl, HIP_SYMBOL(g_Wtl));
  hipGetSymbolAddress((void**)&deg,    HIP_SYMBOL(g_deg));
  hipGetSymbolAddress((void**)&rowptr, HIP_SYMBOL(g_rowptr));
  hipGetSymbolAddress((void**)&cursor, HIP_SYMBOL(g_cursor));
  hipGetSymbolAddress((void**)&adj,    HIP_SYMBOL(g_adj));
  hipGetSymbolAddress((void**)&bsum,   HIP_SYMBOL(g_bsum));

  // ---- weight transpose + split + BK=64 tile-swizzle (once per launch) ----
  k_wtrans<<<dim3(2, 4, 2),  256, 0, stream>>>(w_in1, Wth + OFF_IN1, Wtl + OFF_IN1, 128);
  k_wtrans<<<dim3(6, 4, 2),  256, 0, stream>>>(w_in2, Wth + OFF_IN2, Wtl + OFF_IN2, 384);
  k_wtrans<<<dim3(6, 4, 2),  256, 0, stream>>>(w_in3, Wth + OFF_IN3, Wtl + OFF_IN3, 384);
  k_wtrans<<<dim3(4, 4, 24), 256, 0, stream>>>(w_h1,  Wth + OFF_H1,  Wtl + OFF_H1,  256);
  k_wtrans<<<dim3(4, 4, 24), 256, 0, stream>>>(w_h2,  Wth + OFF_H2,  Wtl + OFF_H2,  256);
  k_wtrans<<<dim3(4, 4, 24), 256, 0, stream>>>(w_h3,  Wth + OFF_H3,  Wtl + OFF_H3,  256);

  const int BIG = 0x7fffffff;

  auto layerGrid = [](int N) { return dim3((unsigned)(((N + 127) / 128) * 2)); };

  auto build_csr = [&](const int* edges, int E, int N) {
    hipMemsetAsync(deg, 0, (size_t)N * sizeof(int), stream);
    k_count<<<(E + 255) / 256, 256, 0, stream>>>(edges, deg, E);
    int nb = (N + 1023) / 1024;
    k_scan_part<<<nb, 256, 0, stream>>>(deg, bsum, N);
    k_scan_top<<<1, 128, 0, stream>>>(bsum, nb);
    k_scan_write<<<nb, 256, 0, stream>>>(deg, bsum, rowptr, cursor, N);
    k_fill<<<(E + 255) / 256, 256, 0, stream>>>(edges, cursor, adj, E);
  };

  auto gconv_hidden = [&](size_t offH, const float* bh, int N) {
    unsigned short *Xh = Ah, *Xl = Al, *Yh = Bh, *Yl = Bl;
    for (int l = 0; l < 12; ++l) {
      const unsigned short* w0h = Wth + offH + (size_t)(2 * l + 0) * 65536;
      const unsigned short* w0l = Wtl + offH + (size_t)(2 * l + 0) * 65536;
      const unsigned short* w1h = Wth + offH + (size_t)(2 * l + 1) * 65536;
      const unsigned short* w1l = Wtl + offH + (size_t)(2 * l + 1) * 65536;
      const float* b0 = bh + (size_t)l * 2 * HID;
      const float* b1 = b0 + HID;
      k_gather<256><<<((size_t)N * 32 + 255) / 256, 256, 0, stream>>>(
          rowptr, adj, Xh, Xl, Gh, Gl, N);
      Panels pd = {{Xh, Gh, nullptr, nullptr}, {Xl, Gl, nullptr, nullptr},
                   {0, 256, BIG, BIG}, {256, 256, 0, 0}};
      k_layer<<<layerGrid(N), 512, 0, stream>>>(pd, 512, w0h, w0l, w1h, w1l, 256,
                                                b0, b1, deg, Yh, Yl, N);
      std::swap(Xh, Yh);
      std::swap(Xl, Yl);
    }
    // x ends in A planes (12 swaps)
  };

  auto gconv_out = [&](const unsigned short* Xh, const unsigned short* Xl,
                       const float* wo, const float* bo,
                       float* Cdst, const int* edges, int E, int N) {
    k_rowdot6<<<((size_t)N * 64 + 255) / 256, 256, 0, stream>>>(Xh, Xl, wo, bo, Cdst, C2, N);
    k_scatter3<<<(E + 255) / 256, 256, 0, stream>>>(edges, C2, Cdst, E);
  };

  // ---------- Stage 1 ----------
  build_csr(edges1, E1, N1);
  k_transpose<<<56 * 56, 128, 0, stream>>>(conv64, T, 56 * 56);
  k_vert_align<<<N1, 128, 0, stream>>>(T, verts0, VAh, VAl, N1, 56, 56);
  k_gather<128><<<((size_t)N1 * 16 + 255) / 256, 256, 0, stream>>>(
      rowptr, adj, VAh, VAl, Gh, Gl, N1);
  {
    Panels pd = {{VAh, Gh, nullptr, nullptr}, {VAl, Gl, nullptr, nullptr},
                 {0, 128, BIG, BIG}, {128, 128, 0, 0}};
    k_layer<<<layerGrid(N1), 512, 0, stream>>>(pd, 256,
        Wth + OFF_IN1, Wtl + OFF_IN1, Wth + OFF_IN1 + 32768, Wtl + OFF_IN1 + 32768, 128,
        b_in1, b_in1 + HID, deg, Ah, Al, N1);
  }
  gconv_hidden(OFF_H1, b_h1, N1);                          // x -> A planes
  gconv_out(Ah, Al, w_out1, b_out1, C0, edges1, E1, N1);   // c1 -> C0
  k_subdiv3<<<(N2 + 255) / 256, 256, 0, stream>>>(C0, edges1, Vv, N1, E1);  // v2
  k_subdiv_feat<<<((size_t)N2 * 32 + 255) / 256, 256, 0, stream>>>(
      Ah, Al, edges1, Dh, Dl, N1, E1);                                      // hs -> D

  // ---------- Stage 2 ----------
  build_csr(edges2, E2, N2);
  k_transpose<<<28 * 28, 128, 0, stream>>>(conv128, T, 28 * 28);
  k_vert_align<<<N2, 128, 0, stream>>>(T, Vv, VAh, VAl, N2, 28, 28);
  k_gather<128><<<((size_t)N2 * 16 + 255) / 256, 256, 0, stream>>>(
      rowptr, adj, VAh, VAl, Gh, Gl, N2);
  k_gather<256><<<((size_t)N2 * 32 + 255) / 256, 256, 0, stream>>>(
      rowptr, adj, Dh, Dl, Bh, Bl, N2);
  {
    const size_t m0 = OFF_IN2, m1 = OFF_IN2 + (size_t)256 * 384;
    Panels pd = {{VAh, Dh, Gh, Bh}, {VAl, Dl, Gl, Bl},
                 {0, 128, 384, 512}, {128, 256, 128, 256}};
    k_layer<<<layerGrid(N2), 512, 0, stream>>>(pd, 768,
        Wth + m0, Wtl + m0, Wth + m1, Wtl + m1, 384,
        b_in2, b_in2 + HID, deg, Ah, Al, N2);
  }
  gconv_hidden(OFF_H2, b_h2, N2);                          // x -> A planes
  gconv_out(Ah, Al, w_out2, b_out2, C0, edges2, E2, N2);   // c2 -> C0
  k_subdiv3<<<(N3 + 255) / 256, 256, 0, stream>>>(C0, edges2, Vv, N2, E2);  // v3
  k_subdiv_feat<<<((size_t)N3 * 32 + 255) / 256, 256, 0, stream>>>(
      Ah, Al, edges2, Dh, Dl, N2, E2);                                      // hs -> D

  // ---------- Stage 3 ----------
  build_csr(edges3, E3, N3);
  k_transpose<<<14 * 14, 128, 0, stream>>>(conv256, T, 14 * 14);
  k_vert_align<<<N3, 128, 0, stream>>>(T, Vv, VAh, VAl, N3, 14, 14);
  k_gather<128><<<((size_t)N3 * 16 + 255) / 256, 256, 0, stream>>>(
      rowptr, adj, VAh, VAl, Gh, Gl, N3);
  k_gather<256><<<((size_t)N3 * 32 + 255) / 256, 256, 0, stream>>>(
      rowptr, adj, Dh, Dl, Bh, Bl, N3);
  {
    const size_t m0 = OFF_IN3, m1 = OFF_IN3 + (size_t)256 * 384;
    Panels pd = {{VAh, Dh, Gh, Bh}, {VAl, Dl, Gl, Bl},
                 {0, 128, 384, 512}, {128, 256, 128, 256}};
    k_layer<<<layerGrid(N3), 512, 0, stream>>>(pd, 768,
        Wth + m0, Wtl + m0, Wth + m1, Wtl + m1, 384,
        b_in3, b_in3 + HID, deg, Ah, Al, N3);
  }
  gconv_hidden(OFF_H3, b_h3, N3);                          // x -> A planes
  float* OUT = (float*)d_out;
  k_rowdot6<<<((size_t)N3 * 64 + 255) / 256, 256, 0, stream>>>(
      Ah, Al, w_out3, b_out3, OUT, C2, N3);
  k_scatter3<<<(E3 + 255) / 256, 256, 0, stream>>>(edges3, C2, OUT, E3);
}

// Round 15
// 3821.524 us; speedup vs baseline: 1.2597x; 1.0218x over previous
//
#include <hip/hip_runtime.h>
#include <utility>

#define HID 256

typedef __attribute__((ext_vector_type(8))) short bf16x8;
typedef __attribute__((ext_vector_type(4))) float f32x4;
typedef __attribute__((ext_vector_type(4))) unsigned short us4;
typedef __attribute__((ext_vector_type(8))) unsigned short us8;

// Topology constants for GRID_N=80
constexpr size_t MAXN3 = 100489;
constexpr size_t MAXE3 = 300200;

// Tiled-weight offsets (elements). Per matrix: [4 cb][K/64 ktb][4096 bf16],
// tile content pre-swizzled so a LINEAR global_load_lds produces the swizzled image.
constexpr size_t OFF_IN1 = 0;                       // 2 mats K=128
constexpr size_t OFF_IN2 = OFF_IN1 + 2 * 256 * 128; // 2 mats K=384
constexpr size_t OFF_IN3 = OFF_IN2 + 2 * 256 * 384;
constexpr size_t OFF_H1  = OFF_IN3 + 2 * 256 * 384; // 24 mats K=256
constexpr size_t OFF_H2  = OFF_H1 + 24 * 256 * 256;
constexpr size_t OFF_H3  = OFF_H2 + 24 * 256 * 256;
constexpr size_t WT_TOTAL = OFF_H3 + 24 * 256 * 256;

// Static device scratch (BSS — graph-capture safe). Features = split bf16
// hi/lo PLANES: x == b2f(hi) + b2f(lo) exactly.
__device__ __attribute__((aligned(16))) unsigned short g_Ah[MAXN3 * 256];
__device__ __attribute__((aligned(16))) unsigned short g_Al[MAXN3 * 256];
__device__ __attribute__((aligned(16))) unsigned short g_Bh[MAXN3 * 256];
__device__ __attribute__((aligned(16))) unsigned short g_Bl[MAXN3 * 256];
__device__ __attribute__((aligned(16))) unsigned short g_Gh[MAXN3 * 256];
__device__ __attribute__((aligned(16))) unsigned short g_Gl[MAXN3 * 256];
__device__ __attribute__((aligned(16))) unsigned short g_Dh[MAXN3 * 256];
__device__ __attribute__((aligned(16))) unsigned short g_Dl[MAXN3 * 256];
__device__ __attribute__((aligned(16))) unsigned short g_VAh[MAXN3 * 128];
__device__ __attribute__((aligned(16))) unsigned short g_VAl[MAXN3 * 128];
__device__ float g_C0[MAXN3 * 3];
__device__ float g_C2[MAXN3 * 3];
__device__ float g_Vv[MAXN3 * 3];
__device__ float g_T [56 * 56 * 128];
__device__ __attribute__((aligned(16))) unsigned short g_Wth[WT_TOTAL];
__device__ __attribute__((aligned(16))) unsigned short g_Wtl[WT_TOTAL];
// CSR scratch
__device__ int g_deg   [MAXN3];
__device__ int g_rowptr[MAXN3 + 1];
__device__ int g_cursor[MAXN3];
__device__ int g_adj   [2 * MAXE3];
__device__ int g_bsum  [128];

__device__ inline float b2f(unsigned short h) {
  return __uint_as_float((unsigned)h << 16);
}
__device__ inline void fsplit(float f, unsigned short& h, unsigned short& l) {
  unsigned u = __float_as_uint(f);
  h = (unsigned short)(u >> 16);
  float hf = __uint_as_float(u & 0xffff0000u);
  l = (unsigned short)(__float_as_uint(f - hf) >> 16);
}

#define GLOAD16(g, l)                                                       \
  __builtin_amdgcn_global_load_lds(                                        \
      (const __attribute__((address_space(1))) unsigned*)(const void*)(g), \
      (__attribute__((address_space(3))) unsigned*)(void*)(l), 16, 0, 0)

// ---------------- weight transpose + split + tile-swizzle (BK=64 tiles) ----------------
// Out tile chunk c (n=c>>3, sp=c&7) holds W^T[cb*64+n][ktb*64+(sp^(n&7))*8 .. +7]
__global__ __launch_bounds__(256) void k_wtrans(const float* __restrict__ W,
                                                unsigned short* __restrict__ Oh,
                                                unsigned short* __restrict__ Ol,
                                                int K) {
  __shared__ float Ls[64][65];
  int ktb = blockIdx.x, cb = blockIdx.y, mat = blockIdx.z;
  int nktb = gridDim.x;
  const float* Wm = W + (size_t)mat * K * 256;
  int t = threadIdx.x;
#pragma unroll
  for (int i = 0; i < 16; ++i) {
    int idx = i * 256 + t;
    int kk = idx >> 6, cc = idx & 63;
    Ls[kk][cc] = Wm[(size_t)(ktb * 64 + kk) * 256 + cb * 64 + cc];
  }
  __syncthreads();
  size_t tb = ((size_t)(mat * 4 + cb) * nktb + ktb) * 4096;
#pragma unroll
  for (int i = 0; i < 2; ++i) {
    int c = t * 2 + i;
    int n = c >> 3, sp = c & 7;
    int kbase = (sp ^ (n & 7)) * 8;
    unsigned short hb[8], lb[8];
#pragma unroll
    for (int j = 0; j < 8; ++j) {
      float v = Ls[kbase + j][n];
      unsigned short hi, lo;
      fsplit(v, hi, lo);
      hb[j] = hi;
      lb[j] = lo;
    }
    *(us4*)(Oh + tb + c * 8)     = (us4){hb[0], hb[1], hb[2], hb[3]};
    *(us4*)(Oh + tb + c * 8 + 4) = (us4){hb[4], hb[5], hb[6], hb[7]};
    *(us4*)(Ol + tb + c * 8)     = (us4){lb[0], lb[1], lb[2], lb[3]};
    *(us4*)(Ol + tb + c * 8 + 4) = (us4){lb[4], lb[5], lb[6], lb[7]};
  }
}

// ---------------- CSR build (parallel scan) ----------------

__global__ __launch_bounds__(256) void k_count(const int* __restrict__ edges,
                                               int* __restrict__ deg, int E) {
  int e = blockIdx.x * blockDim.x + threadIdx.x;
  if (e >= E) return;
  atomicAdd(&deg[edges[2 * e + 0]], 1);
  atomicAdd(&deg[edges[2 * e + 1]], 1);
}

__global__ __launch_bounds__(256) void k_scan_part(const int* __restrict__ deg,
                                                   int* __restrict__ bsum, int N) {
  __shared__ int s[256];
  int t = threadIdx.x;
  int base = blockIdx.x * 1024 + t * 4;
  int v = 0;
#pragma unroll
  for (int i = 0; i < 4; ++i) {
    int idx = base + i;
    if (idx < N) v += deg[idx];
  }
  s[t] = v;
  __syncthreads();
  for (int off = 128; off > 0; off >>= 1) {
    if (t < off) s[t] += s[t + off];
    __syncthreads();
  }
  if (t == 0) bsum[blockIdx.x] = s[0];
}

__global__ __launch_bounds__(128) void k_scan_top(int* __restrict__ bsum, int nb) {
  __shared__ int s[128];
  int t = threadIdx.x;
  s[t] = (t < nb) ? bsum[t] : 0;
  __syncthreads();
  for (int off = 1; off < 128; off <<= 1) {
    int v = (t >= off) ? s[t - off] : 0;
    __syncthreads();
    s[t] += v;
    __syncthreads();
  }
  if (t < nb) bsum[t] = (t == 0) ? 0 : s[t - 1];
}

__global__ __launch_bounds__(256) void k_scan_write(const int* __restrict__ deg,
                                                    const int* __restrict__ bsum,
                                                    int* __restrict__ rowptr,
                                                    int* __restrict__ cursor, int N) {
  __shared__ int s[256];
  int t = threadIdx.x;
  int base = blockIdx.x * 1024;
  int d[4];
  int local = 0;
#pragma unroll
  for (int i = 0; i < 4; ++i) {
    int idx = base + t * 4 + i;
    d[i] = (idx < N) ? deg[idx] : 0;
    local += d[i];
  }
  s[t] = local;
  __syncthreads();
  for (int off = 1; off < 256; off <<= 1) {
    int v = (t >= off) ? s[t - off] : 0;
    __syncthreads();
    s[t] += v;
    __syncthreads();
  }
  int run = bsum[blockIdx.x] + s[t] - local;
#pragma unroll
  for (int i = 0; i < 4; ++i) {
    int idx = base + t * 4 + i;
    if (idx < N) {
      rowptr[idx] = run;
      cursor[idx] = run;
    }
    run += d[i];
  }
  if (blockIdx.x == gridDim.x - 1 && t == 255) rowptr[N] = run;
}

__global__ __launch_bounds__(256) void k_fill(const int* __restrict__ edges,
                                              int* __restrict__ cursor,
                                              int* __restrict__ adj, int E) {
  int e = blockIdx.x * blockDim.x + threadIdx.x;
  if (e >= E) return;
  int a = edges[2 * e + 0];
  int b = edges[2 * e + 1];
  adj[atomicAdd(&cursor[a], 1)] = b;
  adj[atomicAdd(&cursor[b], 1)] = a;
}

// ---------------- misc kernels ----------------

__global__ __launch_bounds__(128) void k_transpose(const float* __restrict__ in,
                                                   float* __restrict__ out, int HW) {
  int p = blockIdx.x;
  int c = threadIdx.x;
  if (p < HW) out[(size_t)p * 128 + c] = in[(size_t)c * HW + p];
}

__global__ __launch_bounds__(128) void k_vert_align(const float* __restrict__ fT,
                                                    const float* __restrict__ verts,
                                                    unsigned short* __restrict__ oh,
                                                    unsigned short* __restrict__ ol,
                                                    int N, int H, int W) {
  int v = blockIdx.x;
  if (v >= N) return;
  int c = threadIdx.x;
  float vx = verts[(size_t)v * 3 + 0];
  float vy = verts[(size_t)v * 3 + 1];
  float fx = (vx + 1.f) * 0.5f * (float)(W - 1);
  float fy = (vy + 1.f) * 0.5f * (float)(H - 1);
  float x0f = floorf(fx), y0f = floorf(fy);
  float wx = fx - x0f, wy = fy - y0f;
  int x0 = (int)x0f, y0 = (int)y0f;
  float acc = 0.f;
#pragma unroll
  for (int dy = 0; dy < 2; ++dy) {
#pragma unroll
    for (int dx = 0; dx < 2; ++dx) {
      int yi = y0 + dy, xi = x0 + dx;
      bool valid = (yi >= 0) && (yi < H) && (xi >= 0) && (xi < W);
      int yc = min(max(yi, 0), H - 1);
      int xc = min(max(xi, 0), W - 1);
      float val = fT[((size_t)yc * W + xc) * 128 + c];
      float wgt = (dy ? wy : 1.f - wy) * (dx ? wx : 1.f - wx);
      acc += valid ? val * wgt : 0.f;
    }
  }
  unsigned short h, l;
  fsplit(acc, h, l);
  oh[(size_t)v * 128 + c] = h;
  ol[(size_t)v * 128 + c] = l;
}

// G[v] = split( sum_{u in adj(v)} (b2f(Xh[u]) + b2f(Xl[u])) ), 8 ch/thread
template <int CH>
__global__ __launch_bounds__(256) void k_gather(const int* __restrict__ rowptr,
                                                const int* __restrict__ adj,
                                                const unsigned short* __restrict__ Xh,
                                                const unsigned short* __restrict__ Xl,
                                                unsigned short* __restrict__ Gh,
                                                unsigned short* __restrict__ Gl, int N) {
  constexpr int TPV = CH / 8;
  int idx = blockIdx.x * blockDim.x + threadIdx.x;
  int v = idx / TPV;
  if (v >= N) return;
  int c = (idx % TPV) * 8;
  float a[8] = {};
  int lo = rowptr[v], hi = rowptr[v + 1];
  for (int i = lo; i < hi; ++i) {
    size_t base = (size_t)adj[i] * CH + c;
    us8 h = *(const us8*)(Xh + base);
    us8 l = *(const us8*)(Xl + base);
#pragma unroll
    for (int j = 0; j < 8; ++j) a[j] += b2f(h[j]) + b2f(l[j]);
  }
  us8 oh, ol;
#pragma unroll
  for (int j = 0; j < 8; ++j) {
    unsigned short hh, ll;
    fsplit(a[j], hh, ll);
    oh[j] = hh;
    ol[j] = ll;
  }
  *(us8*)(Gh + (size_t)v * CH + c) = oh;
  *(us8*)(Gl + (size_t)v * CH + c) = ol;
}

// ---- split-plane MFMA layer (128x128 tile, BK=64, single-buffer, 16 waves) ----
struct Panels {
  const unsigned short* ph[4];
  const unsigned short* pl[4];
  int ks[4];
  int ld[4];
};

// involution swizzle: LDS[row][s] holds source chunk s^(row&7); 8-bf16 chunks
#define SWZ(row, slot) (((row) * 64) + (((slot) ^ ((row) & 7)) << 3))

__global__ __launch_bounds__(1024, 2) void k_layer(
    Panels pd, int Kmm,
    const unsigned short* __restrict__ w0h, const unsigned short* __restrict__ w0l,
    const unsigned short* __restrict__ w1h, const unsigned short* __restrict__ w1l,
    int Kw,
    const float* __restrict__ b0, const float* __restrict__ b1,
    const int* __restrict__ deg,
    unsigned short* __restrict__ Yh, unsigned short* __restrict__ Yl, int N) {
  // 64 KB total -> 2 blocks/CU x 16 waves = 32 waves/CU (hardware max)
  __shared__ __attribute__((aligned(16))) unsigned short Xh_lds[128 * 64]; // 16 KB
  __shared__ __attribute__((aligned(16))) unsigned short Xl_lds[128 * 64]; // 16 KB
  __shared__ __attribute__((aligned(16))) unsigned short Wh_lds[2 * 4096]; // 16 KB
  __shared__ __attribute__((aligned(16))) unsigned short Wl_lds[2 * 4096]; // 16 KB
  int tid = threadIdx.x;
  int lane = tid & 63;
  int wid = tid >> 6;          // 0..15
  int wm = wid >> 2;           // 0..3 (32-row band)
  int wn = wid & 3;            // 0..3 (32-col band)

  // XCD-aware swizzle: groups of 8 row-tiles x 2 col-blocks
  int nrt = (N + 127) >> 7;
  int total = nrt * 2;
  int flat = blockIdx.x;
  int rowtile, colblk;
  if ((flat & ~15) + 16 <= total) {
    int sub = flat & 15;
    rowtile = (flat >> 4) * 8 + (sub & 7);
    colblk = sub >> 3;
  } else {
    rowtile = flat >> 1;
    colblk = flat & 1;
  }
  int row0 = rowtile * 128;
  int col0 = colblk * 128;
  int nktbw = Kw >> 6;

  f32x4 acc[2][2];
#pragma unroll
  for (int m = 0; m < 2; ++m)
#pragma unroll
    for (int n = 0; n < 2; ++n) acc[m][n] = (f32x4){0.f, 0.f, 0.f, 0.f};

  for (int kt = 0; kt < Kmm; kt += 64) {
    int pi = (kt >= pd.ks[1]) + (kt >= pd.ks[2]) + (kt >= pd.ks[3]);
    const unsigned short* bph = pd.ph[pi];
    const unsigned short* bpl = pd.pl[pi];
    int ld = pd.ld[pi];
    int koff = kt - pd.ks[pi];
    // ---- X stage: 1024 16B-chunks per plane, 1 per thread; chunk c:
    //      row=c>>3, slot=c&7; source pre-swizzled chunk = slot^(row&7).
    {
      int c = tid;
      int row = c >> 3, slot = c & 7;
      int vg = min(row0 + row, N - 1);
      size_t so = (size_t)vg * ld + koff + ((slot ^ (row & 7)) << 3);
      GLOAD16(bph + so, &Xh_lds[(size_t)c * 8]);
      GLOAD16(bpl + so, &Xl_lds[(size_t)c * 8]);
    }
    // ---- W stage: two 64-col pre-swizzled tiles per plane, 1 chunk/thread
    {
      int ktb = (kt < Kw) ? (kt >> 6) : ((kt - Kw) >> 6);
      const unsigned short* mh = (kt < Kw) ? w0h : w1h;
      const unsigned short* ml = (kt < Kw) ? w0l : w1l;
      int c = tid;
      int half = c >> 9, ci = c & 511;
      size_t tb = ((size_t)((2 * colblk + half) * nktbw + ktb)) * 4096 + (size_t)ci * 8;
      GLOAD16(mh + tb, &Wh_lds[half * 4096 + ci * 8]);
      GLOAD16(ml + tb, &Wl_lds[half * 4096 + ci * 8]);
    }
    __syncthreads();
    // ---- compute: per ks read 4 A + 4 B (b128), 12 MFMA per wave
#pragma unroll
    for (int ks = 0; ks < 2; ++ks) {
      int slot = ks * 4 + (lane >> 4);
      bf16x8 ah[2], al[2];
#pragma unroll
      for (int m = 0; m < 2; ++m) {
        int row = wm * 32 + m * 16 + (lane & 15);
        int off = SWZ(row, slot);
        ah[m] = *(const bf16x8*)&Xh_lds[off];
        al[m] = *(const bf16x8*)&Xl_lds[off];
      }
      bf16x8 bh[2], bl[2];
#pragma unroll
      for (int n = 0; n < 2; ++n) {
        int nr = wn * 32 + n * 16 + (lane & 15);   // 0..127
        int off = (nr >> 6) * 4096 + SWZ(nr & 63, slot);
        bh[n] = *(const bf16x8*)&Wh_lds[off];
        bl[n] = *(const bf16x8*)&Wl_lds[off];
      }
#pragma unroll
      for (int m = 0; m < 2; ++m)
#pragma unroll
        for (int n = 0; n < 2; ++n) {
          f32x4 c = acc[m][n];
          c = __builtin_amdgcn_mfma_f32_16x16x32_bf16(al[m], bh[n], c, 0, 0, 0);
          c = __builtin_amdgcn_mfma_f32_16x16x32_bf16(ah[m], bl[n], c, 0, 0, 0);
          c = __builtin_amdgcn_mfma_f32_16x16x32_bf16(ah[m], bh[n], c, 0, 0, 0);
          acc[m][n] = c;
        }
    }
    __syncthreads();
  }

  // epilogue: split( v + b0[col] + deg[row]*b1[col] ) into hi/lo planes
#pragma unroll
  for (int m = 0; m < 2; ++m) {
    int rbase = row0 + wm * 32 + m * 16 + (lane >> 4) * 4;
    float dv[4];
#pragma unroll
    for (int r = 0; r < 4; ++r)
      dv[r] = (rbase + r < N) ? (float)deg[rbase + r] : 0.f;
#pragma unroll
    for (int n = 0; n < 2; ++n) {
      int col = col0 + wn * 32 + n * 16 + (lane & 15);
      float bb0 = b0[col], bb1 = b1[col];
      f32x4 v = acc[m][n];
#pragma unroll
      for (int r = 0; r < 4; ++r) {
        int row = rbase + r;
        if (row < N) {
          unsigned short h, l;
          fsplit(v[r] + bb0 + dv[r] * bb1, h, l);
          Yh[(size_t)row * HID + col] = h;
          Yl[(size_t)row * HID + col] = l;
        }
      }
    }
  }
}

// Both 256x3 output heads in one X pass.
__global__ __launch_bounds__(256) void k_rowdot6(const unsigned short* __restrict__ Xh,
                                                 const unsigned short* __restrict__ Xl,
                                                 const float* __restrict__ W,
                                                 const float* __restrict__ b,
                                                 float* __restrict__ Y0,
                                                 float* __restrict__ Y1, int N) {
  int gid = blockIdx.x * blockDim.x + threadIdx.x;
  int row = gid >> 6;
  int lane = threadIdx.x & 63;
  if (row >= N) return;
  size_t base = (size_t)row * HID + lane * 4;
  us4 hv = *(const us4*)(Xh + base);
  us4 lv = *(const us4*)(Xl + base);
  float s[6] = {0.f, 0.f, 0.f, 0.f, 0.f, 0.f};
#pragma unroll
  for (int k = 0; k < 4; ++k) {
    float x = b2f(hv[k]) + b2f(lv[k]);
    int kk = lane * 4 + k;
#pragma unroll
    for (int j = 0; j < 3; ++j) {
      s[j]     += x * W[kk * 3 + j];
      s[3 + j] += x * W[768 + kk * 3 + j];
    }
  }
#pragma unroll
  for (int off = 32; off > 0; off >>= 1)
#pragma unroll
    for (int j = 0; j < 6; ++j) s[j] += __shfl_down(s[j], off);
  if (lane == 0) {
#pragma unroll
    for (int j = 0; j < 3; ++j) {
      Y0[(size_t)row * 3 + j] = s[j] + b[j];
      Y1[(size_t)row * 3 + j] = s[3 + j] + b[3 + j];
    }
  }
}

__global__ __launch_bounds__(256) void k_scatter3(const int* __restrict__ edges,
                                                  const float* __restrict__ H,
                                                  float* __restrict__ OUT, int E) {
  int e = blockIdx.x * blockDim.x + threadIdx.x;
  if (e >= E) return;
  int a = edges[(size_t)e * 2 + 0];
  int b = edges[(size_t)e * 2 + 1];
#pragma unroll
  for (int k = 0; k < 3; ++k) {
    atomicAdd(&OUT[(size_t)a * 3 + k], H[(size_t)b * 3 + k]);
    atomicAdd(&OUT[(size_t)b * 3 + k], H[(size_t)a * 3 + k]);
  }
}

__global__ __launch_bounds__(256) void k_subdiv3(const float* __restrict__ c,
                                                 const int* __restrict__ edges,
                                                 float* __restrict__ v, int N, int E) {
  int i = blockIdx.x * blockDim.x + threadIdx.x;
  if (i >= N + E) return;
  if (i < N) {
#pragma unroll
    for (int k = 0; k < 3; ++k) v[(size_t)i * 3 + k] = c[(size_t)i * 3 + k];
  } else {
    int e = i - N;
    int a = edges[(size_t)e * 2 + 0];
    int b = edges[(size_t)e * 2 + 1];
#pragma unroll
    for (int k = 0; k < 3; ++k)
      v[(size_t)i * 3 + k] = 0.5f * (c[(size_t)a * 3 + k] + c[(size_t)b * 3 + k]);
  }
}

// hs = subdiv(x): 8 channels/thread on hi/lo planes
__global__ __launch_bounds__(256) void k_subdiv_feat(const unsigned short* __restrict__ xh,
                                                     const unsigned short* __restrict__ xl,
                                                     const int* __restrict__ edges,
                                                     unsigned short* __restrict__ oh,
                                                     unsigned short* __restrict__ ol,
                                                     int N, int E) {
  int idx = blockIdx.x * blockDim.x + threadIdx.x;
  int v = idx >> 5;
  if (v >= N + E) return;
  int c = (idx & 31) * 8;
  us8 rh, rl;
  if (v < N) {
    rh = *(const us8*)(xh + (size_t)v * HID + c);
    rl = *(const us8*)(xl + (size_t)v * HID + c);
  } else {
    int e = v - N;
    int a = edges[(size_t)e * 2 + 0];
    int b = edges[(size_t)e * 2 + 1];
    us8 ahv = *(const us8*)(xh + (size_t)a * HID + c);
    us8 alv = *(const us8*)(xl + (size_t)a * HID + c);
    us8 bhv = *(const us8*)(xh + (size_t)b * HID + c);
    us8 blv = *(const us8*)(xl + (size_t)b * HID + c);
#pragma unroll
    for (int j = 0; j < 8; ++j) {
      float f = 0.5f * ((b2f(ahv[j]) + b2f(alv[j])) + (b2f(bhv[j]) + b2f(blv[j])));
      unsigned short hh, ll;
      fsplit(f, hh, ll);
      rh[j] = hh;
      rl[j] = ll;
    }
  }
  *(us8*)(oh + (size_t)v * HID + c) = rh;
  *(us8*)(ol + (size_t)v * HID + c) = rl;
}

// ---------------- launcher ----------------

extern "C" void kernel_launch(void* const* d_in, const int* in_sizes, int n_in,
                              void* d_out, int out_size, void* d_ws, size_t ws_size,
                              hipStream_t stream) {
  const float* conv64  = (const float*)d_in[0];
  const float* conv128 = (const float*)d_in[1];
  const float* conv256 = (const float*)d_in[2];
  const float* verts0  = (const float*)d_in[3];
  const int*   edges1  = (const int*)d_in[4];
  const int*   edges2  = (const int*)d_in[5];
  const int*   edges3  = (const int*)d_in[6];
  const float* w_in1 = (const float*)d_in[7],  *b_in1 = (const float*)d_in[8];
  const float* w_h1  = (const float*)d_in[9],  *b_h1  = (const float*)d_in[10];
  const float* w_out1= (const float*)d_in[11], *b_out1= (const float*)d_in[12];
  const float* w_in2 = (const float*)d_in[13], *b_in2 = (const float*)d_in[14];
  const float* w_h2  = (const float*)d_in[15], *b_h2  = (const float*)d_in[16];
  const float* w_out2= (const float*)d_in[17], *b_out2= (const float*)d_in[18];
  const float* w_in3 = (const float*)d_in[19], *b_in3 = (const float*)d_in[20];
  const float* w_h3  = (const float*)d_in[21], *b_h3  = (const float*)d_in[22];
  const float* w_out3= (const float*)d_in[23], *b_out3= (const float*)d_in[24];

  const int N1 = in_sizes[3] / 3;
  const int E1 = in_sizes[4] / 2;
  const int E2 = in_sizes[5] / 2;
  const int E3 = in_sizes[6] / 2;
  const int N2 = N1 + E1;
  const int N3 = N2 + E2;
  if ((size_t)N3 > MAXN3 || (size_t)E3 > MAXE3) return;

  unsigned short *Ah, *Al, *Bh, *Bl, *Gh, *Gl, *Dh, *Dl, *VAh, *VAl;
  float *C0, *C2, *Vv, *T;
  unsigned short *Wth, *Wtl;
  int *deg, *rowptr, *cursor, *adj, *bsum;
  hipGetSymbolAddress((void**)&Ah,  HIP_SYMBOL(g_Ah));
  hipGetSymbolAddress((void**)&Al,  HIP_SYMBOL(g_Al));
  hipGetSymbolAddress((void**)&Bh,  HIP_SYMBOL(g_Bh));
  hipGetSymbolAddress((void**)&Bl,  HIP_SYMBOL(g_Bl));
  hipGetSymbolAddress((void**)&Gh,  HIP_SYMBOL(g_Gh));
  hipGetSymbolAddress((void**)&Gl,  HIP_SYMBOL(g_Gl));
  hipGetSymbolAddress((void**)&Dh,  HIP_SYMBOL(g_Dh));
  hipGetSymbolAddress((void**)&Dl,  HIP_SYMBOL(g_Dl));
  hipGetSymbolAddress((void**)&VAh, HIP_SYMBOL(g_VAh));
  hipGetSymbolAddress((void**)&VAl, HIP_SYMBOL(g_VAl));
  hipGetSymbolAddress((void**)&C0, HIP_SYMBOL(g_C0));
  hipGetSymbolAddress((void**)&C2, HIP_SYMBOL(g_C2));
  hipGetSymbolAddress((void**)&Vv, HIP_SYMBOL(g_Vv));
  hipGetSymbolAddress((void**)&T,  HIP_SYMBOL(g_T));
  hipGetSymbolAddress((void**)&Wth, HIP_SYMBOL(g_Wth));
  hipGetSymbolAddress((void**)&Wtl, HIP_SYMBOL(g_Wtl));
  hipGetSymbolAddress((void**)&deg,    HIP_SYMBOL(g_deg));
  hipGetSymbolAddress((void**)&rowptr, HIP_SYMBOL(g_rowptr));
  hipGetSymbolAddress((void**)&cursor, HIP_SYMBOL(g_cursor));
  hipGetSymbolAddress((void**)&adj,    HIP_SYMBOL(g_adj));
  hipGetSymbolAddress((void**)&bsum,   HIP_SYMBOL(g_bsum));

  // ---- weight transpose + split + BK=64 tile-swizzle (once per launch) ----
  k_wtrans<<<dim3(2, 4, 2),  256, 0, stream>>>(w_in1, Wth + OFF_IN1, Wtl + OFF_IN1, 128);
  k_wtrans<<<dim3(6, 4, 2),  256, 0, stream>>>(w_in2, Wth + OFF_IN2, Wtl + OFF_IN2, 384);
  k_wtrans<<<dim3(6, 4, 2),  256, 0, stream>>>(w_in3, Wth + OFF_IN3, Wtl + OFF_IN3, 384);
  k_wtrans<<<dim3(4, 4, 24), 256, 0, stream>>>(w_h1,  Wth + OFF_H1,  Wtl + OFF_H1,  256);
  k_wtrans<<<dim3(4, 4, 24), 256, 0, stream>>>(w_h2,  Wth + OFF_H2,  Wtl + OFF_H2,  256);
  k_wtrans<<<dim3(4, 4, 24), 256, 0, stream>>>(w_h3,  Wth + OFF_H3,  Wtl + OFF_H3,  256);

  const int BIG = 0x7fffffff;

  auto layerGrid = [](int N) { return dim3((unsigned)(((N + 127) / 128) * 2)); };

  auto build_csr = [&](const int* edges, int E, int N) {
    hipMemsetAsync(deg, 0, (size_t)N * sizeof(int), stream);
    k_count<<<(E + 255) / 256, 256, 0, stream>>>(edges, deg, E);
    int nb = (N + 1023) / 1024;
    k_scan_part<<<nb, 256, 0, stream>>>(deg, bsum, N);
    k_scan_top<<<1, 128, 0, stream>>>(bsum, nb);
    k_scan_write<<<nb, 256, 0, stream>>>(deg, bsum, rowptr, cursor, N);
    k_fill<<<(E + 255) / 256, 256, 0, stream>>>(edges, cursor, adj, E);
  };

  auto gconv_hidden = [&](size_t offH, const float* bh, int N) {
    unsigned short *Xh = Ah, *Xl = Al, *Yh = Bh, *Yl = Bl;
    for (int l = 0; l < 12; ++l) {
      const unsigned short* w0h = Wth + offH + (size_t)(2 * l + 0) * 65536;
      const unsigned short* w0l = Wtl + offH + (size_t)(2 * l + 0) * 65536;
      const unsigned short* w1h = Wth + offH + (size_t)(2 * l + 1) * 65536;
      const unsigned short* w1l = Wtl + offH + (size_t)(2 * l + 1) * 65536;
      const float* b0 = bh + (size_t)l * 2 * HID;
      const float* b1 = b0 + HID;
      k_gather<256><<<((size_t)N * 32 + 255) / 256, 256, 0, stream>>>(
          rowptr, adj, Xh, Xl, Gh, Gl, N);
      Panels pd = {{Xh, Gh, nullptr, nullptr}, {Xl, Gl, nullptr, nullptr},
                   {0, 256, BIG, BIG}, {256, 256, 0, 0}};
      k_layer<<<layerGrid(N), 1024, 0, stream>>>(pd, 512, w0h, w0l, w1h, w1l, 256,
                                                 b0, b1, deg, Yh, Yl, N);
      std::swap(Xh, Yh);
      std::swap(Xl, Yl);
    }
    // x ends in A planes (12 swaps)
  };

  auto gconv_out = [&](const unsigned short* Xh, const unsigned short* Xl,
                       const float* wo, const float* bo,
                       float* Cdst, const int* edges, int E, int N) {
    k_rowdot6<<<((size_t)N * 64 + 255) / 256, 256, 0, stream>>>(Xh, Xl, wo, bo, Cdst, C2, N);
    k_scatter3<<<(E + 255) / 256, 256, 0, stream>>>(edges, C2, Cdst, E);
  };

  // ---------- Stage 1 ----------
  build_csr(edges1, E1, N1);
  k_transpose<<<56 * 56, 128, 0, stream>>>(conv64, T, 56 * 56);
  k_vert_align<<<N1, 128, 0, stream>>>(T, verts0, VAh, VAl, N1, 56, 56);
  k_gather<128><<<((size_t)N1 * 16 + 255) / 256, 256, 0, stream>>>(
      rowptr, adj, VAh, VAl, Gh, Gl, N1);
  {
    Panels pd = {{VAh, Gh, nullptr, nullptr}, {VAl, Gl, nullptr, nullptr},
                 {0, 128, BIG, BIG}, {128, 128, 0, 0}};
    k_layer<<<layerGrid(N1), 1024, 0, stream>>>(pd, 256,
        Wth + OFF_IN1, Wtl + OFF_IN1, Wth + OFF_IN1 + 32768, Wtl + OFF_IN1 + 32768, 128,
        b_in1, b_in1 + HID, deg, Ah, Al, N1);
  }
  gconv_hidden(OFF_H1, b_h1, N1);                          // x -> A planes
  gconv_out(Ah, Al, w_out1, b_out1, C0, edges1, E1, N1);   // c1 -> C0
  k_subdiv3<<<(N2 + 255) / 256, 256, 0, stream>>>(C0, edges1, Vv, N1, E1);  // v2
  k_subdiv_feat<<<((size_t)N2 * 32 + 255) / 256, 256, 0, stream>>>(
      Ah, Al, edges1, Dh, Dl, N1, E1);                                      // hs -> D

  // ---------- Stage 2 ----------
  build_csr(edges2, E2, N2);
  k_transpose<<<28 * 28, 128, 0, stream>>>(conv128, T, 28 * 28);
  k_vert_align<<<N2, 128, 0, stream>>>(T, Vv, VAh, VAl, N2, 28, 28);
  k_gather<128><<<((size_t)N2 * 16 + 255) / 256, 256, 0, stream>>>(
      rowptr, adj, VAh, VAl, Gh, Gl, N2);
  k_gather<256><<<((size_t)N2 * 32 + 255) / 256, 256, 0, stream>>>(
      rowptr, adj, Dh, Dl, Bh, Bl, N2);
  {
    const size_t m0 = OFF_IN2, m1 = OFF_IN2 + (size_t)256 * 384;
    Panels pd = {{VAh, Dh, Gh, Bh}, {VAl, Dl, Gl, Bl},
                 {0, 128, 384, 512}, {128, 256, 128, 256}};
    k_layer<<<layerGrid(N2), 1024, 0, stream>>>(pd, 768,
        Wth + m0, Wtl + m0, Wth + m1, Wtl + m1, 384,
        b_in2, b_in2 + HID, deg, Ah, Al, N2);
  }
  gconv_hidden(OFF_H2, b_h2, N2);                          // x -> A planes
  gconv_out(Ah, Al, w_out2, b_out2, C0, edges2, E2, N2);   // c2 -> C0
  k_subdiv3<<<(N3 + 255) / 256, 256, 0, stream>>>(C0, edges2, Vv, N2, E2);  // v3
  k_subdiv_feat<<<((size_t)N3 * 32 + 255) / 256, 256, 0, stream>>>(
      Ah, Al, edges2, Dh, Dl, N2, E2);                                      // hs -> D

  // ---------- Stage 3 ----------
  build_csr(edges3, E3, N3);
  k_transpose<<<14 * 14, 128, 0, stream>>>(conv256, T, 14 * 14);
  k_vert_align<<<N3, 128, 0, stream>>>(T, Vv, VAh, VAl, N3, 14, 14);
  k_gather<128><<<((size_t)N3 * 16 + 255) / 256, 256, 0, stream>>>(
      rowptr, adj, VAh, VAl, Gh, Gl, N3);
  k_gather<256><<<((size_t)N3 * 32 + 255) / 256, 256, 0, stream>>>(
      rowptr, adj, Dh, Dl, Bh, Bl, N3);
  {
    const size_t m0 = OFF_IN3, m1 = OFF_IN3 + (size_t)256 * 384;
    Panels pd = {{VAh, Dh, Gh, Bh}, {VAl, Dl, Gl, Bl},
                 {0, 128, 384, 512}, {128, 256, 128, 256}};
    k_layer<<<layerGrid(N3), 1024, 0, stream>>>(pd, 768,
        Wth + m0, Wtl + m0, Wth + m1, Wtl + m1, 384,
        b_in3, b_in3 + HID, deg, Ah, Al, N3);
  }
  gconv_hidden(OFF_H3, b_h3, N3);                          // x -> A planes
  float* OUT = (float*)d_out;
  k_rowdot6<<<((size_t)N3 * 64 + 255) / 256, 256, 0, stream>>>(
      Ah, Al, w_out3, b_out3, OUT, C2, N3);
  k_scatter3<<<(E3 + 255) / 256, 256, 0, stream>>>(edges3, C2, OUT, E3);
}